// Round 10
// baseline (377.322 us; speedup 1.0000x reference)
//
#include <hip/hip_runtime.h>
#include <math.h>

#define Bb 8
#define Ll 1024
#define Dd 256
#define Ee 8
#define Hh 1024
#define LMAXc 512
#define NTOK (Bb*Dd)   // 2048
#define LPAD 1032      // 4 + 1024 + 4 padded token rows per batch
#define MAXTILES 72    // worst-case sum_e ceil(cnt[e]/64): 4096/64 + 7

typedef short bf16x8 __attribute__((ext_vector_type(8)));
typedef float f32x4 __attribute__((ext_vector_type(4)));
typedef unsigned short u16x8 __attribute__((ext_vector_type(8)));

__device__ __forceinline__ float gelu_f(float x) {
    return 0.5f * x * (1.0f + erff(x * 0.70710678118654752440f));
}
__device__ __forceinline__ unsigned short f2b(float x) {          // RTN fp32->bf16
    unsigned int u = __float_as_uint(x);
    return (unsigned short)((u + 0x7fffu + ((u >> 16) & 1u)) >> 16);
}
__device__ __forceinline__ float b2f(unsigned short h) {
    return __uint_as_float(((unsigned int)h) << 16);
}
__device__ __forceinline__ void gl_lds16(const void* g, void* l) {
    __builtin_amdgcn_global_load_lds((const __attribute__((address_space(1))) unsigned int*)g,
                                     (__attribute__((address_space(3))) unsigned int*)l, 16, 0, 0);
}
__device__ __forceinline__ void split_one4(const float* __restrict__ src,
                                           unsigned short* __restrict__ hi,
                                           unsigned short* __restrict__ lo, int idx) {
    float4 v = ((const float4*)src)[idx];
    ushort2 h01, h23, l01, l23;
    unsigned short h;
    h = f2b(v.x); h01.x = h; l01.x = f2b(v.x - b2f(h));
    h = f2b(v.y); h01.y = h; l01.y = f2b(v.y - b2f(h));
    h = f2b(v.z); h23.x = h; l23.x = f2b(v.z - b2f(h));
    h = f2b(v.w); h23.y = h; l23.y = f2b(v.w - b2f(h));
    ((ushort2*)hi)[idx * 2] = h01; ((ushort2*)hi)[idx * 2 + 1] = h23;
    ((ushort2*)lo)[idx * 2] = l01; ((ushort2*)lo)[idx * 2 + 1] = l23;
}

// ---------------- standalone splitter (w3, launched after gemm1) ----------------
__global__ __launch_bounds__(256) void split_w4(const float* __restrict__ src,
                                                unsigned short* __restrict__ hi,
                                                unsigned short* __restrict__ lo, int n4) {
    int idx = blockIdx.x * 256 + threadIdx.x;
    if (idx >= n4) return;
    split_one4(src, hi, lo, idx);
}

// ============================================================================
// prep_all: fused prep
//   [0,2048)    : pad+split x -> [B][LPAD][D] bf16 hi/lo planes (interior)
//   [2048,4352) : conv weights [3][D][D][3] -> split planes [layer][k][o][i]
//   [4352,8448) : split w1
//   [8448,16640): split w2
// ============================================================================
__global__ __launch_bounds__(256) void prep_all(
    const float* __restrict__ x, const float* __restrict__ cw,
    const float* __restrict__ w1, const float* __restrict__ w2,
    unsigned short* __restrict__ xhi, unsigned short* __restrict__ xlo,
    unsigned short* __restrict__ wchi, unsigned short* __restrict__ wclo,
    unsigned short* __restrict__ w1hi, unsigned short* __restrict__ w1lo,
    unsigned short* __restrict__ w2hi, unsigned short* __restrict__ w2lo)
{
    int blk = blockIdx.x;
    int t = threadIdx.x;
    if (blk < 2048) {
        int idx = blk * 256 + t;                   // over B*L*D/4 = 524288
        int d4 = idx & 63;
        int l  = (idx >> 6) & 1023;
        int b  = idx >> 16;
        float4 v = ((const float4*)x)[idx];
        size_t o = ((size_t)(b * LPAD + 4 + l) * Dd + d4 * 4) >> 1;
        ushort2 h01, h23, l01, l23;
        unsigned short h;
        h = f2b(v.x); h01.x = h; l01.x = f2b(v.x - b2f(h));
        h = f2b(v.y); h01.y = h; l01.y = f2b(v.y - b2f(h));
        h = f2b(v.z); h23.x = h; l23.x = f2b(v.z - b2f(h));
        h = f2b(v.w); h23.y = h; l23.y = f2b(v.w - b2f(h));
        ((ushort2*)xhi)[o] = h01; ((ushort2*)xhi)[o + 1] = h23;
        ((ushort2*)xlo)[o] = l01; ((ushort2*)xlo)[o + 1] = l23;
    } else if (blk < 4352) {
        int idx = (blk - 2048) * 256 + t;          // 589824 exact
        int i = idx & (Dd - 1);
        int o = (idx >> 8) & (Dd - 1);
        int lk = idx >> 16;
        int layer = lk / 3;
        int k = lk % 3;
        float v = cw[(((size_t)layer * Dd + o) * Dd + i) * 3 + k];
        unsigned short h = f2b(v);
        wchi[idx] = h;
        wclo[idx] = f2b(v - b2f(h));
    } else if (blk < 8448) {
        split_one4(w1, w1hi, w1lo, (blk - 4352) * 256 + t);
    } else {
        split_one4(w2, w2hi, w2lo, (blk - 8448) * 256 + t);
    }
}

// ============================================================================
// conv_mfma: dilated causal-'same' conv as MFMA NT-GEMM over 3 shifted taps.
// 3-pass split-bf16 (router precision). 64x64 tile, 4 waves (2x2 of 32x32).
// BK=64 (two 32-chunks per barrier pair) -> 12 k-iters.  (unchanged from R9)
// ============================================================================
template<int MODE>
__global__ __launch_bounds__(256, 2) void conv_mfma(
    const unsigned short* __restrict__ inhi, const unsigned short* __restrict__ inlo,
    const unsigned short* __restrict__ whiL, const unsigned short* __restrict__ wloL,
    const float* __restrict__ bias,
    unsigned short* __restrict__ outhi, unsigned short* __restrict__ outlo,
    float* __restrict__ outf, int dil)
{
    __shared__ char smem[32768];   // Ahi 8K | Alo 8K | Bhi 8K | Blo 8K (each 2 halves of 4K)
    char* sAhi = smem;
    char* sAlo = smem + 8192;
    char* sBhi = smem + 16384;
    char* sBlo = smem + 24576;

    const int t = threadIdx.x;
    const int lane = t & 63, w = t >> 6;
    const int r16 = lane & 15, quad = lane >> 4;
    const int wr = w >> 1, wc = w & 1;
    const int row0 = blockIdx.x * 64;
    const int col0 = blockIdx.y * 64;
    const int b = row0 >> 10, l0 = row0 & 1023;

    int aoff[2], boff[2];
    #pragma unroll
    for (int i = 0; i < 2; ++i) {
        int ra = wr * 32 + i * 16 + r16;
        aoff[i] = ra * 64 + ((quad ^ ((ra >> 1) & 3)) << 4);
        int rb = wc * 32 + i * 16 + r16;
        boff[i] = rb * 64 + ((quad ^ ((rb >> 1) & 3)) << 4);
    }
    const int rs = t >> 2, ce = ((t & 3) ^ ((rs >> 1) & 3)) << 3;
    const unsigned short* gAhi = inhi + (size_t)(b * LPAD + 4 + l0 + rs) * Dd + ce;
    const unsigned short* gAlo = inlo + (size_t)(b * LPAD + 4 + l0 + rs) * Dd + ce;

    f32x4 acc[2][2];
    const f32x4 zero4 = {0.f, 0.f, 0.f, 0.f};
    #pragma unroll
    for (int i = 0; i < 2; ++i)
        #pragma unroll
        for (int j = 0; j < 2; ++j) acc[i][j] = zero4;

    for (int tap = 0; tap < 3; ++tap) {
        const int sh = (tap - 1) * dil;
        const unsigned short* pAhi = gAhi + sh * Dd;
        const unsigned short* pAlo = gAlo + sh * Dd;
        const unsigned short* gBhi = whiL + ((size_t)tap * Dd + col0 + rs) * Dd + ce;
        const unsigned short* gBlo = wloL + ((size_t)tap * Dd + col0 + rs) * Dd + ce;
        for (int kb = 0; kb < Dd; kb += 64) {
            gl_lds16(pAhi + kb,      sAhi + (w << 10));
            gl_lds16(pAhi + kb + 32, sAhi + 4096 + (w << 10));
            gl_lds16(pAlo + kb,      sAlo + (w << 10));
            gl_lds16(pAlo + kb + 32, sAlo + 4096 + (w << 10));
            gl_lds16(gBhi + kb,      sBhi + (w << 10));
            gl_lds16(gBhi + kb + 32, sBhi + 4096 + (w << 10));
            gl_lds16(gBlo + kb,      sBlo + (w << 10));
            gl_lds16(gBlo + kb + 32, sBlo + 4096 + (w << 10));
            __syncthreads();
            #pragma unroll
            for (int h = 0; h < 2; ++h) {
                const int ho = h * 4096;
                bf16x8 ah[2], al[2], bh[2], bl[2];
                #pragma unroll
                for (int i = 0; i < 2; ++i) {
                    ah[i] = *(const bf16x8*)(sAhi + ho + aoff[i]);
                    al[i] = *(const bf16x8*)(sAlo + ho + aoff[i]);
                    bh[i] = *(const bf16x8*)(sBhi + ho + boff[i]);
                    bl[i] = *(const bf16x8*)(sBlo + ho + boff[i]);
                }
                #pragma unroll
                for (int mi = 0; mi < 2; ++mi)
                    #pragma unroll
                    for (int ni = 0; ni < 2; ++ni) {
                        acc[mi][ni] = __builtin_amdgcn_mfma_f32_16x16x32_bf16(ah[mi], bh[ni], acc[mi][ni], 0, 0, 0);
                        acc[mi][ni] = __builtin_amdgcn_mfma_f32_16x16x32_bf16(ah[mi], bl[ni], acc[mi][ni], 0, 0, 0);
                        acc[mi][ni] = __builtin_amdgcn_mfma_f32_16x16x32_bf16(al[mi], bh[ni], acc[mi][ni], 0, 0, 0);
                    }
            }
            __syncthreads();
        }
    }

    int cc[2]; float bv[2];
    #pragma unroll
    for (int ni = 0; ni < 2; ++ni) {
        cc[ni] = col0 + wc * 32 + ni * 16 + r16;
        bv[ni] = bias[cc[ni]];
    }
    #pragma unroll
    for (int mi = 0; mi < 2; ++mi) {
        int lb = l0 + wr * 32 + mi * 16 + quad * 4;
        #pragma unroll
        for (int reg = 0; reg < 4; ++reg) {
            int l = lb + reg;
            #pragma unroll
            for (int ni = 0; ni < 2; ++ni) {
                float v = gelu_f(acc[mi][ni][reg] + bv[ni]);
                if (MODE == 0) {
                    size_t o = (size_t)(b * LPAD + 4 + l) * Dd + cc[ni];
                    unsigned short h = f2b(v);
                    outhi[o] = h;
                    outlo[o] = f2b(v - b2f(h));
                } else {
                    outf[(size_t)(b * Ll + l) * Dd + cc[ni]] = v;
                }
            }
        }
    }
}

// ============================================================================
// Sparse expert GEMM v5: double-buffered LDS, ONE barrier per K-iteration,
// prefetch issued AFTER the barrier so its latency is covered by the MFMA
// phase (the pre-barrier vmcnt(0) then drains ~compute-phase-old loads).
// BK=32, 2 x 20KB buffers = 40KB; __launch_bounds__(256,4) -> 160KB LDS cap.
// Grid (Hh/128 = 8, MAXTILES): blockIdx.x = N-strip == XCD (L2 locality).
// Tile M=64 x N=128, 4 waves (2x2, wave-tile 32x64), 2-pass split-bf16.
// ============================================================================
template<int MODE, int GATHER>
__global__ __launch_bounds__(256, 4) void gemm_sp(
    const unsigned short* __restrict__ AG,
    const unsigned short* __restrict__ BhiG, const unsigned short* __restrict__ BloG,
    const float* __restrict__ biasG, const float* __restrict__ gates,
    const int* __restrict__ cntG, const int* __restrict__ listG,
    const int* __restrict__ tileTab, const int* __restrict__ ntiles,
    unsigned short* __restrict__ Cout, float* __restrict__ outf,
    int M, int N, int K)
{
    if (blockIdx.y >= ntiles[0]) return;          // uniform early-exit
    const int desc = tileTab[blockIdx.y];
    const int e = desc >> 16;
    const int row0 = (desc & 0xffff) * 64;
    const int cn = cntG[e];

    __shared__ char smem[40960];                  // 2 bufs x (A 4K | Bhi0 4K | Bhi1 4K | Blo0 4K | Blo1 4K)

    const unsigned short* Bhi = BhiG + (size_t)e * N * K;
    const unsigned short* Blo = BloG + (size_t)e * N * K;
    const float* bias = biasG + (size_t)e * N;

    const int t = threadIdx.x;
    const int lane = t & 63, w = t >> 6;
    const int r16 = lane & 15, quad = lane >> 4;
    const int wr = w >> 1, wc = w & 1;
    const int col0 = blockIdx.x * 128;

    int aoff[2], boff[4];
    #pragma unroll
    for (int i = 0; i < 2; ++i) {
        int ra = wr * 32 + i * 16 + r16;
        aoff[i] = ra * 64 + ((quad ^ ((ra >> 1) & 3)) << 4);
    }
    #pragma unroll
    for (int j = 0; j < 4; ++j) {
        int rb = wc * 64 + j * 16 + r16;
        boff[j] = rb * 64 + ((quad ^ ((rb >> 1) & 3)) << 4);
    }
    // staging: A 256 slots (slot t); B 2x256 slots/plane (r0s, r1s)
    const int r0s = t >> 2, c0s = ((t & 3) ^ ((r0s >> 1) & 3)) << 3;
    const int r1s = r0s + 64, c1s = ((t & 3) ^ ((r1s >> 1) & 3)) << 3;
    int ri = row0 + r0s; if (ri > cn - 1) ri = cn - 1;
    const int ar = GATHER ? listG[e * NTOK + ri] : ri;
    const unsigned short* gA  = AG + ((size_t)e * M + ar) * K + c0s;
    const unsigned short* gBhi0 = Bhi + (size_t)(col0 + r0s) * K + c0s;
    const unsigned short* gBhi1 = Bhi + (size_t)(col0 + r1s) * K + c1s;
    const unsigned short* gBlo0 = Blo + (size_t)(col0 + r0s) * K + c0s;
    const unsigned short* gBlo1 = Blo + (size_t)(col0 + r1s) * K + c1s;
    const int wofs = w << 10;

    f32x4 acc[2][4];
    const f32x4 zero4 = {0.f, 0.f, 0.f, 0.f};
    #pragma unroll
    for (int i = 0; i < 2; ++i)
        #pragma unroll
        for (int j = 0; j < 4; ++j) acc[i][j] = zero4;

    // prologue: stage tile 0 into buf 0, wait once
    {
        char* buf = smem;
        gl_lds16(gA,    buf + wofs);
        gl_lds16(gBhi0, buf + 4096 + wofs);
        gl_lds16(gBhi1, buf + 8192 + wofs);
        gl_lds16(gBlo0, buf + 12288 + wofs);
        gl_lds16(gBlo1, buf + 16384 + wofs);
    }
    __syncthreads();

    for (int k0 = 0; k0 < K; k0 += 32) {
        char* cur = smem + (((k0 >> 5) & 1) ? 20480 : 0);
        const int kn = k0 + 32;
        if (kn < K) {
            // prefetch AFTER barrier: latency overlapped by the MFMA phase below
            char* nxt = smem + (((kn >> 5) & 1) ? 20480 : 0);
            gl_lds16(gA + kn,    nxt + wofs);
            gl_lds16(gBhi0 + kn, nxt + 4096 + wofs);
            gl_lds16(gBhi1 + kn, nxt + 8192 + wofs);
            gl_lds16(gBlo0 + kn, nxt + 12288 + wofs);
            gl_lds16(gBlo1 + kn, nxt + 16384 + wofs);
        }
        bf16x8 ah[2], bh[4], bl[4];
        #pragma unroll
        for (int i = 0; i < 2; ++i) ah[i] = *(const bf16x8*)(cur + aoff[i]);
        #pragma unroll
        for (int j = 0; j < 4; ++j) {
            bh[j] = *(const bf16x8*)(cur + 4096 + boff[j]);
            bl[j] = *(const bf16x8*)(cur + 12288 + boff[j]);
        }
        #pragma unroll
        for (int mi = 0; mi < 2; ++mi)
            #pragma unroll
            for (int ni = 0; ni < 4; ++ni) {
                acc[mi][ni] = __builtin_amdgcn_mfma_f32_16x16x32_bf16(ah[mi], bh[ni], acc[mi][ni], 0, 0, 0);
                acc[mi][ni] = __builtin_amdgcn_mfma_f32_16x16x32_bf16(ah[mi], bl[ni], acc[mi][ni], 0, 0, 0);
            }
        __syncthreads();   // drains prefetch (aged by compute) + guards buf reuse
    }

    int cc[4]; float bv[4];
    #pragma unroll
    for (int ni = 0; ni < 4; ++ni) {
        cc[ni] = col0 + wc * 64 + ni * 16 + r16;
        bv[ni] = bias[cc[ni]];
    }
    if (MODE == 0) {
        unsigned short* CE = Cout + (size_t)e * M * N;
        #pragma unroll
        for (int mi = 0; mi < 2; ++mi) {
            int rb = row0 + wr * 32 + mi * 16 + quad * 4;
            #pragma unroll
            for (int reg = 0; reg < 4; ++reg) {
                size_t roff = (size_t)(rb + reg) * N;
                #pragma unroll
                for (int ni = 0; ni < 4; ++ni)
                    CE[roff + cc[ni]] = f2b(gelu_f(acc[mi][ni][reg] + bv[ni]));
            }
        }
    } else {
        #pragma unroll
        for (int mi = 0; mi < 2; ++mi) {
            int rb = row0 + wr * 32 + mi * 16 + quad * 4;
            #pragma unroll
            for (int reg = 0; reg < 4; ++reg) {
                int i = rb + reg;
                if (i < cn) {
                    int tok = listG[e * NTOK + i];
                    float g = gates[(size_t)tok * Ee + e];
                    size_t roff = (size_t)tok * N;
                    #pragma unroll
                    for (int ni = 0; ni < 4; ++ni)
                        atomicAdd(&outf[roff + cc[ni]], g * (acc[mi][ni][reg] + bv[ni]));
                }
            }
        }
    }
}

// ============================ router tail + downsample ==============================

__global__ __launch_bounds__(256) void logits_accum(const float* __restrict__ h,
                                                    const float* __restrict__ fl_w,
                                                    float* __restrict__ logits) {
    int b = blockIdx.x;
    int chunk = blockIdx.y;
    __shared__ float wsm[Ee][128];
    for (int i = threadIdx.x; i < Ee * 128; i += 256) {
        int e = i >> 7, l = i & 127;
        wsm[e][l] = fl_w[e * Ll + chunk * 128 + l];
    }
    __syncthreads();
    int d = threadIdx.x;
    float acc[Ee] = {};
    for (int l = 0; l < 128; ++l) {
        float v = h[((size_t)b * Ll + chunk * 128 + l) * Dd + d];
        #pragma unroll
        for (int e = 0; e < Ee; ++e) acc[e] += v * wsm[e][l];
    }
    int tok = b * Dd + d;
    #pragma unroll
    for (int e = 0; e < Ee; ++e) atomicAdd(&logits[tok * Ee + e], acc[e]);
}

// sigmoid -> softmax -> top2 -> gates + per-expert lists + balanced tile table.
// ONE block of 1024 threads (2 toks each) so cnt is final before table build.
__global__ __launch_bounds__(1024) void gates_final(const float* __restrict__ logits,
                                                    const float* __restrict__ fl_b,
                                                    float* __restrict__ gates,
                                                    int* __restrict__ cnt,
                                                    int* __restrict__ list,
                                                    int* __restrict__ tileTab,
                                                    int* __restrict__ ntiles) {
    for (int tok = threadIdx.x; tok < NTOK; tok += 1024) {
        float s[Ee];
        #pragma unroll
        for (int e = 0; e < Ee; ++e) {
            float z = logits[tok * Ee + e] + fl_b[e];
            s[e] = 1.0f / (1.0f + expf(-z));
        }
        float mx = s[0];
        #pragma unroll
        for (int e = 1; e < Ee; ++e) mx = fmaxf(mx, s[e]);
        float p[Ee];
        #pragma unroll
        for (int e = 0; e < Ee; ++e) p[e] = expf(s[e] - mx);
        int i1 = 0;
        #pragma unroll
        for (int e = 1; e < Ee; ++e) if (p[e] > p[i1]) i1 = e;
        int i2 = (i1 == 0) ? 1 : 0;
        #pragma unroll
        for (int e = 0; e < Ee; ++e) {
            if (e == i1 || e == i2) continue;
            if (p[e] > p[i2]) i2 = e;
        }
        float inv = 1.0f / (p[i1] + p[i2]);
        #pragma unroll
        for (int e = 0; e < Ee; ++e) gates[tok * Ee + e] = 0.0f;
        gates[tok * Ee + i1] = p[i1] * inv;
        gates[tok * Ee + i2] = p[i2] * inv;
        int p1 = atomicAdd(&cnt[i1], 1);
        list[i1 * NTOK + p1] = tok;
        int p2 = atomicAdd(&cnt[i2], 1);
        list[i2 * NTOK + p2] = tok;
    }
    __syncthreads();
    if (threadIdx.x == 0) {
        int nt = 0;
        for (int e = 0; e < Ee; ++e) {
            int c = atomicAdd(&cnt[e], 0);        // coherent read (atomics bypass L1)
            for (int m = 0; m * 64 < c; ++m) tileTab[nt++] = (e << 16) | m;
        }
        ntiles[0] = nt;
    }
}

// downsample v3: single bf16 plane, valid region only (xe pad cols hit zero
// w1 cols). 8 j/thread, r-outer for load ILP; early-exit past Li.
__global__ __launch_bounds__(256) void downsample_v3(const float* __restrict__ x,
                                                     unsigned short* __restrict__ xe) {
    int e = blockIdx.z;
    int f = e + 2;
    int Li = Ll / f;
    int j0 = blockIdx.x * 8;
    if (j0 >= Li) return;
    int b = blockIdx.y;
    int d = threadIdx.x;
    float invf = 1.0f / (float)f;
    int lim = Li - 1;
    float v[8] = {};
    for (int r = 0; r < f; ++r) {
        #pragma unroll
        for (int jj = 0; jj < 8; ++jj) {
            int j = j0 + jj; if (j > lim) j = lim;
            v[jj] += x[((size_t)(b * Ll + j * f + r)) * Dd + d];
        }
    }
    size_t obase = ((size_t)(e * NTOK + b * 256 + d)) * LMAXc + j0;
    if (j0 + 8 <= Li) {
        u16x8 hv;
        #pragma unroll
        for (int q = 0; q < 8; ++q) hv[q] = (short)f2b(v[q] * invf);
        *(u16x8*)(xe + obase) = hv;
    } else {
        for (int jj = 0; jj < Li - j0; ++jj)
            xe[obase + jj] = f2b(v[jj] * invf);
    }
}

__global__ __launch_bounds__(256) void transpose_out(const float* __restrict__ outacc,
                                                     float* __restrict__ out) {
    __shared__ float tile[32][33];
    int b = blockIdx.z;
    int d0 = blockIdx.x * 32;
    int o0 = blockIdx.y * 32;
    int tx = threadIdx.x & 31, ty = threadIdx.x >> 5;
    for (int i = 0; i < 32; i += 8)
        tile[ty + i][tx] = outacc[((size_t)b * Dd + d0 + ty + i) * Hh + o0 + tx];
    __syncthreads();
    for (int i = 0; i < 32; i += 8)
        out[((size_t)b * Hh + o0 + ty + i) * Dd + d0 + tx] = tile[tx][ty + i];
}

extern "C" void kernel_launch(void* const* d_in, const int* in_sizes, int n_in,
                              void* d_out, int out_size, void* d_ws, size_t ws_size,
                              hipStream_t stream) {
    const float* x       = (const float*)d_in[0];
    const float* conv_w  = (const float*)d_in[1];
    const float* conv_b  = (const float*)d_in[2];
    const float* fl_w    = (const float*)d_in[3];
    const float* fl_b    = (const float*)d_in[4];
    const float* w1      = (const float*)d_in[5];
    const float* b1      = (const float*)d_in[6];
    const float* w2      = (const float*)d_in[7];
    const float* b2      = (const float*)d_in[8];
    const float* w3      = (const float*)d_in[9];
    const float* b3      = (const float*)d_in[10];
    float* out = (float*)d_out;

    char* ws = (char*)d_ws;
    // Workspace (peak ~151.2 MB, proven). Layout identical to R7-R9.
    unsigned short* xphi = (unsigned short*)(ws);
    unsigned short* xplo = (unsigned short*)(ws + 4227072);
    unsigned short* cphi = (unsigned short*)(ws + 8454144);
    unsigned short* cplo = (unsigned short*)(ws + 12681216);
    unsigned short* wchi = (unsigned short*)(ws + 16908288);
    unsigned short* wclo = (unsigned short*)(ws + 18087936);
    float* hL            = (float*)(ws + 19267584);
    unsigned short* h1   = (unsigned short*)(ws);
    unsigned short* h2   = (unsigned short*)(ws + 33554432);
    unsigned short* xe   = (unsigned short*)(ws + 67108864);
    unsigned short* w3hi = (unsigned short*)(ws + 67108864);
    unsigned short* w3lo = (unsigned short*)(ws + 83886080);
    unsigned short* w1hi = (unsigned short*)(ws + 100663296);
    unsigned short* w1lo = (unsigned short*)(ws + 109051904);
    unsigned short* w2hi = (unsigned short*)(ws + 117440512);
    unsigned short* w2lo = (unsigned short*)(ws + 134217728);
    float* logits  = (float*)(ws + 150994944);
    int*   cnt     = (int*)(ws + 151060480);
    int*   ntiles  = (int*)(ws + 151060512);
    int*   tileTab = (int*)(ws + 151060544);
    float* gates   = (float*)(ws + 151061504);
    int*   list    = (int*)(ws + 151127040);
    float* outacc  = (float*)(ws);

    // zero: padded conv buffers (pad rows), and logits+cnt+ntiles in one shot
    hipMemsetAsync(ws, 0, 16908288, stream);
    hipMemsetAsync(logits, 0, 65536 + 64, stream);

    prep_all<<<16640, 256, 0, stream>>>(x, conv_w, w1, w2,
                                        xphi, xplo, wchi, wclo,
                                        w1hi, w1lo, w2hi, w2lo);

    // Router convs on MFMA (3-pass split — ~1e-7 relative, safe for discrete top-2)
    const int WL = 3 * Dd * Dd;
    conv_mfma<0><<<dim3(Bb * Ll / 64, Dd / 64), 256, 0, stream>>>(
        xphi, xplo, wchi + 0 * WL, wclo + 0 * WL, conv_b + 0 * Dd, cphi, cplo, nullptr, 1);
    conv_mfma<0><<<dim3(Bb * Ll / 64, Dd / 64), 256, 0, stream>>>(
        cphi, cplo, wchi + 1 * WL, wclo + 1 * WL, conv_b + 1 * Dd, xphi, xplo, nullptr, 2);
    conv_mfma<1><<<dim3(Bb * Ll / 64, Dd / 64), 256, 0, stream>>>(
        xphi, xplo, wchi + 2 * WL, wclo + 2 * WL, conv_b + 2 * Dd, nullptr, nullptr, hL, 4);

    logits_accum<<<dim3(Bb, 8), 256, 0, stream>>>(hL, fl_w, logits);
    gates_final<<<1, 1024, 0, stream>>>(logits, fl_b, gates, cnt, list, tileTab, ntiles);

    downsample_v3<<<dim3(64, Bb, Ee), 256, 0, stream>>>(x, xe);

    // GEMM1 sparse (gathered A from xe, K=512): h1 compact over dead conv region
    gemm_sp<0, 1><<<dim3(Hh / 128, MAXTILES), 256, 0, stream>>>(
        xe, w1hi, w1lo, b1, nullptr, cnt, list, tileTab, ntiles, h1, nullptr, NTOK, Hh, LMAXc);

    // xe dead: split w3 into its slot
    split_w4<<<8192, 256, 0, stream>>>(w3, w3hi, w3lo, Ee * Hh * Hh / 4);

    // GEMM2 sparse (compact->compact, K=1024)
    gemm_sp<0, 0><<<dim3(Hh / 128, MAXTILES), 256, 0, stream>>>(
        h1, w2hi, w2lo, b2, nullptr, cnt, list, tileTab, ntiles, h2, nullptr, NTOK, Hh, Hh);

    // h1 dead: zero outacc in its slot
    hipMemsetAsync(outacc, 0, (size_t)NTOK * Hh * sizeof(float), stream);

    // GEMM3 sparse (compact A, gated scatter-add combine)
    gemm_sp<1, 0><<<dim3(Hh / 128, MAXTILES), 256, 0, stream>>>(
        h2, w3hi, w3lo, b3, gates, cnt, list, tileTab, ntiles, nullptr, outacc, NTOK, Hh, Hh);

    transpose_out<<<dim3(Dd / 32, Hh / 32, Bb), 256, 0, stream>>>(outacc, out);
}

// Round 11
// 329.122 us; speedup vs baseline: 1.1465x; 1.1465x over previous
//
#include <hip/hip_runtime.h>
#include <math.h>

#define Bb 8
#define Ll 1024
#define Dd 256
#define Ee 8
#define Hh 1024
#define LMAXc 512
#define NTOK (Bb*Dd)   // 2048
#define LPAD 1032      // 4 + 1024 + 4 padded token rows per batch
#define MAXTILES 72    // worst-case sum_e ceil(cnt[e]/64): 4096/64 + 7

typedef short bf16x8 __attribute__((ext_vector_type(8)));
typedef float f32x4 __attribute__((ext_vector_type(4)));
typedef unsigned short u16x8 __attribute__((ext_vector_type(8)));

__device__ __forceinline__ float gelu_f(float x) {
    return 0.5f * x * (1.0f + erff(x * 0.70710678118654752440f));
}
__device__ __forceinline__ unsigned short f2b(float x) {          // RTN fp32->bf16
    unsigned int u = __float_as_uint(x);
    return (unsigned short)((u + 0x7fffu + ((u >> 16) & 1u)) >> 16);
}
__device__ __forceinline__ float b2f(unsigned short h) {
    return __uint_as_float(((unsigned int)h) << 16);
}
__device__ __forceinline__ void gl_lds16(const void* g, void* l) {
    __builtin_amdgcn_global_load_lds((const __attribute__((address_space(1))) unsigned int*)g,
                                     (__attribute__((address_space(3))) unsigned int*)l, 16, 0, 0);
}
__device__ __forceinline__ void split_one4(const float* __restrict__ src,
                                           unsigned short* __restrict__ hi,
                                           unsigned short* __restrict__ lo, int idx) {
    float4 v = ((const float4*)src)[idx];
    ushort2 h01, h23, l01, l23;
    unsigned short h;
    h = f2b(v.x); h01.x = h; l01.x = f2b(v.x - b2f(h));
    h = f2b(v.y); h01.y = h; l01.y = f2b(v.y - b2f(h));
    h = f2b(v.z); h23.x = h; l23.x = f2b(v.z - b2f(h));
    h = f2b(v.w); h23.y = h; l23.y = f2b(v.w - b2f(h));
    ((ushort2*)hi)[idx * 2] = h01; ((ushort2*)hi)[idx * 2 + 1] = h23;
    ((ushort2*)lo)[idx * 2] = l01; ((ushort2*)lo)[idx * 2 + 1] = l23;
}
__device__ __forceinline__ void cvt_one4(const float* __restrict__ src,
                                         unsigned short* __restrict__ dst, int idx) {
    float4 v = ((const float4*)src)[idx];
    ushort2 h01, h23;
    h01.x = f2b(v.x); h01.y = f2b(v.y);
    h23.x = f2b(v.z); h23.y = f2b(v.w);
    ((ushort2*)dst)[idx * 2] = h01; ((ushort2*)dst)[idx * 2 + 1] = h23;
}

// ============================================================================
// prep_all: fused prep (one launch, all weight/input conversions + pad-zero)
//   [0,2048)      : pad+split x -> [B][LPAD][D] bf16 hi/lo planes (interior)
//   [2048,4352)   : conv weights [3][D][D][3] -> split planes [layer][k][o][i]
//   [4352,8448)   : split w1 (hi/lo)
//   [8448,16640)  : convert w2 -> plain bf16
//   [16640,24832) : convert w3 -> plain bf16
//   [24832,24864) : zero pad rows of xphi/xplo/cphi/cplo (ws is 0xAA-poisoned)
// ============================================================================
__global__ __launch_bounds__(256) void prep_all(
    const float* __restrict__ x, const float* __restrict__ cw,
    const float* __restrict__ w1, const float* __restrict__ w2,
    const float* __restrict__ w3,
    unsigned short* __restrict__ xhi, unsigned short* __restrict__ xlo,
    unsigned short* __restrict__ chi, unsigned short* __restrict__ clo,
    unsigned short* __restrict__ wchi, unsigned short* __restrict__ wclo,
    unsigned short* __restrict__ w1hi, unsigned short* __restrict__ w1lo,
    unsigned short* __restrict__ w2b, unsigned short* __restrict__ w3b)
{
    int blk = blockIdx.x;
    int t = threadIdx.x;
    if (blk < 2048) {
        int idx = blk * 256 + t;                   // over B*L*D/4 = 524288
        int d4 = idx & 63;
        int l  = (idx >> 6) & 1023;
        int b  = idx >> 16;
        float4 v = ((const float4*)x)[idx];
        size_t o = ((size_t)(b * LPAD + 4 + l) * Dd + d4 * 4) >> 1;
        ushort2 h01, h23, l01, l23;
        unsigned short h;
        h = f2b(v.x); h01.x = h; l01.x = f2b(v.x - b2f(h));
        h = f2b(v.y); h01.y = h; l01.y = f2b(v.y - b2f(h));
        h = f2b(v.z); h23.x = h; l23.x = f2b(v.z - b2f(h));
        h = f2b(v.w); h23.y = h; l23.y = f2b(v.w - b2f(h));
        ((ushort2*)xhi)[o] = h01; ((ushort2*)xhi)[o + 1] = h23;
        ((ushort2*)xlo)[o] = l01; ((ushort2*)xlo)[o + 1] = l23;
    } else if (blk < 4352) {
        int idx = (blk - 2048) * 256 + t;          // 589824 exact
        int i = idx & (Dd - 1);
        int o = (idx >> 8) & (Dd - 1);
        int lk = idx >> 16;
        int layer = lk / 3;
        int k = lk % 3;
        float v = cw[(((size_t)layer * Dd + o) * Dd + i) * 3 + k];
        unsigned short h = f2b(v);
        wchi[idx] = h;
        wclo[idx] = f2b(v - b2f(h));
    } else if (blk < 8448) {
        split_one4(w1, w1hi, w1lo, (blk - 4352) * 256 + t);
    } else if (blk < 16640) {
        cvt_one4(w2, w2b, (blk - 8448) * 256 + t);
    } else if (blk < 24832) {
        cvt_one4(w3, w3b, (blk - 16640) * 256 + t);
    } else {
        // zero pad rows: 4 buffers x (8 batches x 8 rows x 256 elems), 8 elems/thread
        int u = (blk - 24832) * 256 + t;           // [0, 8192)
        int f = u >> 11;                           // buffer
        int rem = u & 2047;
        int b = rem >> 8;                          // batch
        int r2 = rem & 255;
        int row = r2 >> 5;                         // 0..7
        int col = (r2 & 31) * 8;
        int padrow = (row < 4) ? row : (1024 + row);
        unsigned short* buf = (f == 0) ? xhi : (f == 1) ? xlo : (f == 2) ? chi : clo;
        u16x8 z = {0, 0, 0, 0, 0, 0, 0, 0};
        *(u16x8*)(buf + (size_t)(b * LPAD + padrow) * Dd + col) = z;
    }
}

// ============================================================================
// conv_mfma: dilated causal-'same' conv as MFMA NT-GEMM over 3 shifted taps.
// 3-pass split-bf16 (router precision). 64x64 tile, 4 waves (2x2 of 32x32).
// BK=64 (two 32-chunks per barrier pair).  (unchanged from R9)
// ============================================================================
template<int MODE>
__global__ __launch_bounds__(256, 2) void conv_mfma(
    const unsigned short* __restrict__ inhi, const unsigned short* __restrict__ inlo,
    const unsigned short* __restrict__ whiL, const unsigned short* __restrict__ wloL,
    const float* __restrict__ bias,
    unsigned short* __restrict__ outhi, unsigned short* __restrict__ outlo,
    float* __restrict__ outf, int dil)
{
    __shared__ char smem[32768];   // Ahi 8K | Alo 8K | Bhi 8K | Blo 8K (each 2 halves of 4K)
    char* sAhi = smem;
    char* sAlo = smem + 8192;
    char* sBhi = smem + 16384;
    char* sBlo = smem + 24576;

    const int t = threadIdx.x;
    const int lane = t & 63, w = t >> 6;
    const int r16 = lane & 15, quad = lane >> 4;
    const int wr = w >> 1, wc = w & 1;
    const int row0 = blockIdx.x * 64;
    const int col0 = blockIdx.y * 64;
    const int b = row0 >> 10, l0 = row0 & 1023;

    int aoff[2], boff[2];
    #pragma unroll
    for (int i = 0; i < 2; ++i) {
        int ra = wr * 32 + i * 16 + r16;
        aoff[i] = ra * 64 + ((quad ^ ((ra >> 1) & 3)) << 4);
        int rb = wc * 32 + i * 16 + r16;
        boff[i] = rb * 64 + ((quad ^ ((rb >> 1) & 3)) << 4);
    }
    const int rs = t >> 2, ce = ((t & 3) ^ ((rs >> 1) & 3)) << 3;
    const unsigned short* gAhi = inhi + (size_t)(b * LPAD + 4 + l0 + rs) * Dd + ce;
    const unsigned short* gAlo = inlo + (size_t)(b * LPAD + 4 + l0 + rs) * Dd + ce;

    f32x4 acc[2][2];
    const f32x4 zero4 = {0.f, 0.f, 0.f, 0.f};
    #pragma unroll
    for (int i = 0; i < 2; ++i)
        #pragma unroll
        for (int j = 0; j < 2; ++j) acc[i][j] = zero4;

    for (int tap = 0; tap < 3; ++tap) {
        const int sh = (tap - 1) * dil;
        const unsigned short* pAhi = gAhi + sh * Dd;
        const unsigned short* pAlo = gAlo + sh * Dd;
        const unsigned short* gBhi = whiL + ((size_t)tap * Dd + col0 + rs) * Dd + ce;
        const unsigned short* gBlo = wloL + ((size_t)tap * Dd + col0 + rs) * Dd + ce;
        for (int kb = 0; kb < Dd; kb += 64) {
            gl_lds16(pAhi + kb,      sAhi + (w << 10));
            gl_lds16(pAhi + kb + 32, sAhi + 4096 + (w << 10));
            gl_lds16(pAlo + kb,      sAlo + (w << 10));
            gl_lds16(pAlo + kb + 32, sAlo + 4096 + (w << 10));
            gl_lds16(gBhi + kb,      sBhi + (w << 10));
            gl_lds16(gBhi + kb + 32, sBhi + 4096 + (w << 10));
            gl_lds16(gBlo + kb,      sBlo + (w << 10));
            gl_lds16(gBlo + kb + 32, sBlo + 4096 + (w << 10));
            __syncthreads();
            #pragma unroll
            for (int h = 0; h < 2; ++h) {
                const int ho = h * 4096;
                bf16x8 ah[2], al[2], bh[2], bl[2];
                #pragma unroll
                for (int i = 0; i < 2; ++i) {
                    ah[i] = *(const bf16x8*)(sAhi + ho + aoff[i]);
                    al[i] = *(const bf16x8*)(sAlo + ho + aoff[i]);
                    bh[i] = *(const bf16x8*)(sBhi + ho + boff[i]);
                    bl[i] = *(const bf16x8*)(sBlo + ho + boff[i]);
                }
                #pragma unroll
                for (int mi = 0; mi < 2; ++mi)
                    #pragma unroll
                    for (int ni = 0; ni < 2; ++ni) {
                        acc[mi][ni] = __builtin_amdgcn_mfma_f32_16x16x32_bf16(ah[mi], bh[ni], acc[mi][ni], 0, 0, 0);
                        acc[mi][ni] = __builtin_amdgcn_mfma_f32_16x16x32_bf16(ah[mi], bl[ni], acc[mi][ni], 0, 0, 0);
                        acc[mi][ni] = __builtin_amdgcn_mfma_f32_16x16x32_bf16(al[mi], bh[ni], acc[mi][ni], 0, 0, 0);
                    }
            }
            __syncthreads();
        }
    }

    int cc[2]; float bv[2];
    #pragma unroll
    for (int ni = 0; ni < 2; ++ni) {
        cc[ni] = col0 + wc * 32 + ni * 16 + r16;
        bv[ni] = bias[cc[ni]];
    }
    #pragma unroll
    for (int mi = 0; mi < 2; ++mi) {
        int lb = l0 + wr * 32 + mi * 16 + quad * 4;
        #pragma unroll
        for (int reg = 0; reg < 4; ++reg) {
            int l = lb + reg;
            #pragma unroll
            for (int ni = 0; ni < 2; ++ni) {
                float v = gelu_f(acc[mi][ni][reg] + bv[ni]);
                if (MODE == 0) {
                    size_t o = (size_t)(b * LPAD + 4 + l) * Dd + cc[ni];
                    unsigned short h = f2b(v);
                    outhi[o] = h;
                    outlo[o] = f2b(v - b2f(h));
                } else {
                    outf[(size_t)(b * Ll + l) * Dd + cc[ni]] = v;
                }
            }
        }
    }
}

// ============================================================================
// Sparse expert GEMM v6 (R9 structure, no dbuf): balanced flat tile dispatch,
// XCD-aligned N-strips, BK=64 (two 32-chunks per barrier pair).
// TWOPASS=1: B = hi+lo split planes (GEMM1/w1). TWOPASS=0: B plain bf16.
// Grid (Hh/128 = 8, MAXTILES): blockIdx.x = N-strip == XCD (L2 locality).
// Tile M=64 x N=128, 4 waves (2x2, wave-tile 32x64), fp32 accum.
// ============================================================================
template<int MODE, int GATHER, int TWOPASS>
__global__ __launch_bounds__(256, 4) void gemm_sp(
    const unsigned short* __restrict__ AG,
    const unsigned short* __restrict__ BhiG, const unsigned short* __restrict__ BloG,
    const float* __restrict__ biasG, const float* __restrict__ gates,
    const int* __restrict__ cntG, const int* __restrict__ listG,
    const int* __restrict__ tileTab, const int* __restrict__ ntiles,
    unsigned short* __restrict__ Cout, float* __restrict__ outf,
    int M, int N, int K)
{
    if (blockIdx.y >= ntiles[0]) return;          // uniform early-exit
    const int desc = tileTab[blockIdx.y];
    const int e = desc >> 16;
    const int row0 = (desc & 0xffff) * 64;
    const int cn = cntG[e];

    __shared__ char smem[TWOPASS ? 40960 : 24576]; // A 8K | Bhi 16K [| Blo 16K]
    char* sA   = smem;
    char* sBhi = smem + 8192;
    char* sBlo = smem + 24576;                    // used only when TWOPASS

    const unsigned short* Bhi = BhiG + (size_t)e * N * K;
    const unsigned short* Blo = TWOPASS ? (BloG + (size_t)e * N * K) : nullptr;
    const float* bias = biasG + (size_t)e * N;

    const int t = threadIdx.x;
    const int lane = t & 63, w = t >> 6;
    const int r16 = lane & 15, quad = lane >> 4;
    const int wr = w >> 1, wc = w & 1;
    const int col0 = blockIdx.x * 128;

    int aoff[2], boff[4];
    #pragma unroll
    for (int i = 0; i < 2; ++i) {
        int ra = wr * 32 + i * 16 + r16;
        aoff[i] = ra * 64 + ((quad ^ ((ra >> 1) & 3)) << 4);
    }
    #pragma unroll
    for (int j = 0; j < 4; ++j) {
        int rb = wc * 64 + j * 16 + r16;
        boff[j] = rb * 64 + ((quad ^ ((rb >> 1) & 3)) << 4);
    }
    // staging: A 256 slots (slot t); B 2x256 slots/plane-half (r0s, r1s)
    const int r0s = t >> 2, c0s = ((t & 3) ^ ((r0s >> 1) & 3)) << 3;
    const int r1s = r0s + 64, c1s = ((t & 3) ^ ((r1s >> 1) & 3)) << 3;
    int ri = row0 + r0s; if (ri > cn - 1) ri = cn - 1;
    const int ar = GATHER ? listG[e * NTOK + ri] : ri;
    const unsigned short* gA  = AG + ((size_t)e * M + ar) * K + c0s;
    const unsigned short* gBhi0 = Bhi + (size_t)(col0 + r0s) * K + c0s;
    const unsigned short* gBhi1 = Bhi + (size_t)(col0 + r1s) * K + c1s;
    const unsigned short* gBlo0 = TWOPASS ? (Blo + (size_t)(col0 + r0s) * K + c0s) : nullptr;
    const unsigned short* gBlo1 = TWOPASS ? (Blo + (size_t)(col0 + r1s) * K + c1s) : nullptr;
    const int wofs = w << 10;

    f32x4 acc[2][4];
    const f32x4 zero4 = {0.f, 0.f, 0.f, 0.f};
    #pragma unroll
    for (int i = 0; i < 2; ++i)
        #pragma unroll
        for (int j = 0; j < 4; ++j) acc[i][j] = zero4;

    for (int k0 = 0; k0 < K; k0 += 64) {
        gl_lds16(gA + k0,          sA + wofs);
        gl_lds16(gA + k0 + 32,     sA + 4096 + wofs);
        gl_lds16(gBhi0 + k0,       sBhi + wofs);
        gl_lds16(gBhi1 + k0,       sBhi + 4096 + wofs);
        gl_lds16(gBhi0 + k0 + 32,  sBhi + 8192 + wofs);
        gl_lds16(gBhi1 + k0 + 32,  sBhi + 12288 + wofs);
        if (TWOPASS) {
            gl_lds16(gBlo0 + k0,       sBlo + wofs);
            gl_lds16(gBlo1 + k0,       sBlo + 4096 + wofs);
            gl_lds16(gBlo0 + k0 + 32,  sBlo + 8192 + wofs);
            gl_lds16(gBlo1 + k0 + 32,  sBlo + 12288 + wofs);
        }
        __syncthreads();
        #pragma unroll
        for (int h = 0; h < 2; ++h) {
            const int ao = h * 4096, bo = h * 8192;
            bf16x8 ah[2], bh[4];
            #pragma unroll
            for (int i = 0; i < 2; ++i) ah[i] = *(const bf16x8*)(sA + ao + aoff[i]);
            #pragma unroll
            for (int j = 0; j < 4; ++j) bh[j] = *(const bf16x8*)(sBhi + bo + boff[j]);
            #pragma unroll
            for (int mi = 0; mi < 2; ++mi)
                #pragma unroll
                for (int ni = 0; ni < 4; ++ni)
                    acc[mi][ni] = __builtin_amdgcn_mfma_f32_16x16x32_bf16(ah[mi], bh[ni], acc[mi][ni], 0, 0, 0);
            if (TWOPASS) {
                bf16x8 bl[4];
                #pragma unroll
                for (int j = 0; j < 4; ++j) bl[j] = *(const bf16x8*)(sBlo + bo + boff[j]);
                #pragma unroll
                for (int mi = 0; mi < 2; ++mi)
                    #pragma unroll
                    for (int ni = 0; ni < 4; ++ni)
                        acc[mi][ni] = __builtin_amdgcn_mfma_f32_16x16x32_bf16(ah[mi], bl[ni], acc[mi][ni], 0, 0, 0);
            }
        }
        __syncthreads();
    }

    int cc[4]; float bv[4];
    #pragma unroll
    for (int ni = 0; ni < 4; ++ni) {
        cc[ni] = col0 + wc * 64 + ni * 16 + r16;
        bv[ni] = bias[cc[ni]];
    }
    if (MODE == 0) {
        unsigned short* CE = Cout + (size_t)e * M * N;
        #pragma unroll
        for (int mi = 0; mi < 2; ++mi) {
            int rb = row0 + wr * 32 + mi * 16 + quad * 4;
            #pragma unroll
            for (int reg = 0; reg < 4; ++reg) {
                size_t roff = (size_t)(rb + reg) * N;
                #pragma unroll
                for (int ni = 0; ni < 4; ++ni)
                    CE[roff + cc[ni]] = f2b(gelu_f(acc[mi][ni][reg] + bv[ni]));
            }
        }
    } else {
        #pragma unroll
        for (int mi = 0; mi < 2; ++mi) {
            int rb = row0 + wr * 32 + mi * 16 + quad * 4;
            #pragma unroll
            for (int reg = 0; reg < 4; ++reg) {
                int i = rb + reg;
                if (i < cn) {
                    int tok = listG[e * NTOK + i];
                    float g = gates[(size_t)tok * Ee + e];
                    size_t roff = (size_t)tok * N;
                    #pragma unroll
                    for (int ni = 0; ni < 4; ++ni)
                        atomicAdd(&outf[roff + cc[ni]], g * (acc[mi][ni][reg] + bv[ni]));
                }
            }
        }
    }
}

// ============================ router tail + downsample ==============================

__global__ __launch_bounds__(256) void logits_accum(const float* __restrict__ h,
                                                    const float* __restrict__ fl_w,
                                                    float* __restrict__ logits) {
    int b = blockIdx.x;
    int chunk = blockIdx.y;
    __shared__ float wsm[Ee][128];
    for (int i = threadIdx.x; i < Ee * 128; i += 256) {
        int e = i >> 7, l = i & 127;
        wsm[e][l] = fl_w[e * Ll + chunk * 128 + l];
    }
    __syncthreads();
    int d = threadIdx.x;
    float acc[Ee] = {};
    for (int l = 0; l < 128; ++l) {
        float v = h[((size_t)b * Ll + chunk * 128 + l) * Dd + d];
        #pragma unroll
        for (int e = 0; e < Ee; ++e) acc[e] += v * wsm[e][l];
    }
    int tok = b * Dd + d;
    #pragma unroll
    for (int e = 0; e < Ee; ++e) atomicAdd(&logits[tok * Ee + e], acc[e]);
}

// sigmoid -> softmax -> top2 -> gates + per-expert lists + balanced tile table.
// ONE block of 1024 threads (2 toks each) so cnt is final before table build.
__global__ __launch_bounds__(1024) void gates_final(const float* __restrict__ logits,
                                                    const float* __restrict__ fl_b,
                                                    float* __restrict__ gates,
                                                    int* __restrict__ cnt,
                                                    int* __restrict__ list,
                                                    int* __restrict__ tileTab,
                                                    int* __restrict__ ntiles) {
    for (int tok = threadIdx.x; tok < NTOK; tok += 1024) {
        float s[Ee];
        #pragma unroll
        for (int e = 0; e < Ee; ++e) {
            float z = logits[tok * Ee + e] + fl_b[e];
            s[e] = 1.0f / (1.0f + expf(-z));
        }
        float mx = s[0];
        #pragma unroll
        for (int e = 1; e < Ee; ++e) mx = fmaxf(mx, s[e]);
        float p[Ee];
        #pragma unroll
        for (int e = 0; e < Ee; ++e) p[e] = expf(s[e] - mx);
        int i1 = 0;
        #pragma unroll
        for (int e = 1; e < Ee; ++e) if (p[e] > p[i1]) i1 = e;
        int i2 = (i1 == 0) ? 1 : 0;
        #pragma unroll
        for (int e = 0; e < Ee; ++e) {
            if (e == i1 || e == i2) continue;
            if (p[e] > p[i2]) i2 = e;
        }
        float inv = 1.0f / (p[i1] + p[i2]);
        #pragma unroll
        for (int e = 0; e < Ee; ++e) gates[tok * Ee + e] = 0.0f;
        gates[tok * Ee + i1] = p[i1] * inv;
        gates[tok * Ee + i2] = p[i2] * inv;
        int p1 = atomicAdd(&cnt[i1], 1);
        list[i1 * NTOK + p1] = tok;
        int p2 = atomicAdd(&cnt[i2], 1);
        list[i2 * NTOK + p2] = tok;
    }
    __syncthreads();
    if (threadIdx.x == 0) {
        int nt = 0;
        for (int e = 0; e < Ee; ++e) {
            int c = atomicAdd(&cnt[e], 0);        // coherent read (atomics bypass L1)
            for (int m = 0; m * 64 < c; ++m) tileTab[nt++] = (e << 16) | m;
        }
        ntiles[0] = nt;
    }
}

// downsample v3: single bf16 plane, valid region only (xe pad cols hit zero
// w1 cols). 8 j/thread, r-outer for load ILP; early-exit past Li.
__global__ __launch_bounds__(256) void downsample_v3(const float* __restrict__ x,
                                                     unsigned short* __restrict__ xe) {
    int e = blockIdx.z;
    int f = e + 2;
    int Li = Ll / f;
    int j0 = blockIdx.x * 8;
    if (j0 >= Li) return;
    int b = blockIdx.y;
    int d = threadIdx.x;
    float invf = 1.0f / (float)f;
    int lim = Li - 1;
    float v[8] = {};
    for (int r = 0; r < f; ++r) {
        #pragma unroll
        for (int jj = 0; jj < 8; ++jj) {
            int j = j0 + jj; if (j > lim) j = lim;
            v[jj] += x[((size_t)(b * Ll + j * f + r)) * Dd + d];
        }
    }
    size_t obase = ((size_t)(e * NTOK + b * 256 + d)) * LMAXc + j0;
    if (j0 + 8 <= Li) {
        u16x8 hv;
        #pragma unroll
        for (int q = 0; q < 8; ++q) hv[q] = (short)f2b(v[q] * invf);
        *(u16x8*)(xe + obase) = hv;
    } else {
        for (int jj = 0; jj < Li - j0; ++jj)
            xe[obase + jj] = f2b(v[jj] * invf);
    }
}

__global__ __launch_bounds__(256) void transpose_out(const float* __restrict__ outacc,
                                                     float* __restrict__ out) {
    __shared__ float tile[32][33];
    int b = blockIdx.z;
    int d0 = blockIdx.x * 32;
    int o0 = blockIdx.y * 32;
    int tx = threadIdx.x & 31, ty = threadIdx.x >> 5;
    for (int i = 0; i < 32; i += 8)
        tile[ty + i][tx] = outacc[((size_t)b * Dd + d0 + ty + i) * Hh + o0 + tx];
    __syncthreads();
    for (int i = 0; i < 32; i += 8)
        out[((size_t)b * Hh + o0 + ty + i) * Dd + d0 + tx] = tile[tx][ty + i];
}

extern "C" void kernel_launch(void* const* d_in, const int* in_sizes, int n_in,
                              void* d_out, int out_size, void* d_ws, size_t ws_size,
                              hipStream_t stream) {
    const float* x       = (const float*)d_in[0];
    const float* conv_w  = (const float*)d_in[1];
    const float* conv_b  = (const float*)d_in[2];
    const float* fl_w    = (const float*)d_in[3];
    const float* fl_b    = (const float*)d_in[4];
    const float* w1      = (const float*)d_in[5];
    const float* b1      = (const float*)d_in[6];
    const float* w2      = (const float*)d_in[7];
    const float* b2      = (const float*)d_in[8];
    const float* w3      = (const float*)d_in[9];
    const float* b3      = (const float*)d_in[10];
    float* out = (float*)d_out;

    char* ws = (char*)d_ws;
    // Workspace (peak ~134.4 MB). h1 region (0..33.5MB) overlaid by conv
    // buffers until gemm1, then by outacc after gemm2:
    //   conv region (under h1):
    //     xphi @ 0           4,227,072  [B][1032][D] bf16 (pads zeroed by prep)
    //     xplo @ 4,227,072   4,227,072
    //     cphi @ 8,454,144   4,227,072
    //     cplo @ 12,681,216  4,227,072
    //     wchi @ 16,908,288  1,179,648
    //     wclo @ 18,087,936  1,179,648
    //     hL   @ 19,267,584  8,388,608  fp32 conv-3 output
    //   h1    @ 0            33,554,432 bf16 compact
    //   h2    @ 33,554,432   33,554,432 bf16 compact
    //   xe    @ 67,108,864   16,777,216 bf16
    //   w1hi  @ 83,886,080    8,388,608
    //   w1lo  @ 92,274,688    8,388,608
    //   w2b   @ 100,663,296  16,777,216 plain bf16
    //   w3b   @ 117,440,512  16,777,216 plain bf16
    //   logits@ 134,217,728      65,536  \ one memset covers
    //   cnt   @ 134,283,264          32  |  logits+cnt+ntiles
    //   ntiles@ 134,283,296           4 /
    //   tileTab@134,283,328         288
    //   gates @ 134,284,288      65,536
    //   list  @ 134,349,824      65,536
    unsigned short* xphi = (unsigned short*)(ws);
    unsigned short* xplo = (unsigned short*)(ws + 4227072);
    unsigned short* cphi = (unsigned short*)(ws + 8454144);
    unsigned short* cplo = (unsigned short*)(ws + 12681216);
    unsigned short* wchi = (unsigned short*)(ws + 16908288);
    unsigned short* wclo = (unsigned short*)(ws + 18087936);
    float* hL            = (float*)(ws + 19267584);
    unsigned short* h1   = (unsigned short*)(ws);
    unsigned short* h2   = (unsigned short*)(ws + 33554432);
    unsigned short* xe   = (unsigned short*)(ws + 67108864);
    unsigned short* w1hi = (unsigned short*)(ws + 83886080);
    unsigned short* w1lo = (unsigned short*)(ws + 92274688);
    unsigned short* w2b  = (unsigned short*)(ws + 100663296);
    unsigned short* w3b  = (unsigned short*)(ws + 117440512);
    float* logits  = (float*)(ws + 134217728);
    int*   cnt     = (int*)(ws + 134283264);
    int*   ntiles  = (int*)(ws + 134283296);
    int*   tileTab = (int*)(ws + 134283328);
    float* gates   = (float*)(ws + 134284288);
    int*   list    = (int*)(ws + 134349824);
    float* outacc  = (float*)(ws);

    // zero logits+cnt+ntiles (pad rows handled inside prep_all)
    hipMemsetAsync(logits, 0, 65536 + 64, stream);

    prep_all<<<24864, 256, 0, stream>>>(x, conv_w, w1, w2, w3,
                                        xphi, xplo, cphi, cplo, wchi, wclo,
                                        w1hi, w1lo, w2b, w3b);

    // Router convs on MFMA (3-pass split — ~1e-7 relative, safe for discrete top-2)
    const int WL = 3 * Dd * Dd;
    conv_mfma<0><<<dim3(Bb * Ll / 64, Dd / 64), 256, 0, stream>>>(
        xphi, xplo, wchi + 0 * WL, wclo + 0 * WL, conv_b + 0 * Dd, cphi, cplo, nullptr, 1);
    conv_mfma<0><<<dim3(Bb * Ll / 64, Dd / 64), 256, 0, stream>>>(
        cphi, cplo, wchi + 1 * WL, wclo + 1 * WL, conv_b + 1 * Dd, xphi, xplo, nullptr, 2);
    conv_mfma<1><<<dim3(Bb * Ll / 64, Dd / 64), 256, 0, stream>>>(
        xphi, xplo, wchi + 2 * WL, wclo + 2 * WL, conv_b + 2 * Dd, nullptr, nullptr, hL, 4);

    logits_accum<<<dim3(Bb, 8), 256, 0, stream>>>(hL, fl_w, logits);
    gates_final<<<1, 1024, 0, stream>>>(logits, fl_b, gates, cnt, list, tileTab, ntiles);

    downsample_v3<<<dim3(64, Bb, Ee), 256, 0, stream>>>(x, xe);

    // GEMM1 sparse (gathered A from xe, K=512, w1 split 2-pass): h1 compact
    gemm_sp<0, 1, 1><<<dim3(Hh / 128, MAXTILES), 256, 0, stream>>>(
        xe, w1hi, w1lo, b1, nullptr, cnt, list, tileTab, ntiles, h1, nullptr, NTOK, Hh, LMAXc);

    // GEMM2 sparse (compact->compact, K=1024, w2 plain bf16 single-pass)
    gemm_sp<0, 0, 0><<<dim3(Hh / 128, MAXTILES), 256, 0, stream>>>(
        h1, w2b, nullptr, b2, nullptr, cnt, list, tileTab, ntiles, h2, nullptr, NTOK, Hh, Hh);

    // h1 dead: zero outacc in its slot
    hipMemsetAsync(outacc, 0, (size_t)NTOK * Hh * sizeof(float), stream);

    // GEMM3 sparse (compact A, w3 plain bf16, gated scatter-add combine)
    gemm_sp<1, 0, 0><<<dim3(Hh / 128, MAXTILES), 256, 0, stream>>>(
        h2, w3b, nullptr, b3, gates, cnt, list, tileTab, ntiles, nullptr, outacc, NTOK, Hh, Hh);

    transpose_out<<<dim3(Dd / 32, Hh / 32, Bb), 256, 0, stream>>>(outacc, out);
}

// Round 12
// 320.240 us; speedup vs baseline: 1.1782x; 1.0277x over previous
//
#include <hip/hip_runtime.h>
#include <math.h>

#define Bb 8
#define Ll 1024
#define Dd 256
#define Ee 8
#define Hh 1024
#define LMAXc 512
#define NTOK (Bb*Dd)   // 2048
#define LPAD 1032      // 4 + 1024 + 4 padded token rows per batch
#define MAXTILES 72    // worst-case sum_e ceil(cnt[e]/64): 4096/64 + 7

typedef short bf16x8 __attribute__((ext_vector_type(8)));
typedef float f32x4 __attribute__((ext_vector_type(4)));
typedef unsigned short u16x8 __attribute__((ext_vector_type(8)));

__device__ __forceinline__ float gelu_f(float x) {
    return 0.5f * x * (1.0f + erff(x * 0.70710678118654752440f));
}
__device__ __forceinline__ unsigned short f2b(float x) {          // RTN fp32->bf16
    unsigned int u = __float_as_uint(x);
    return (unsigned short)((u + 0x7fffu + ((u >> 16) & 1u)) >> 16);
}
__device__ __forceinline__ float b2f(unsigned short h) {
    return __uint_as_float(((unsigned int)h) << 16);
}
__device__ __forceinline__ void gl_lds16(const void* g, void* l) {
    __builtin_amdgcn_global_load_lds((const __attribute__((address_space(1))) unsigned int*)g,
                                     (__attribute__((address_space(3))) unsigned int*)l, 16, 0, 0);
}
__device__ __forceinline__ void split_one4(const float* __restrict__ src,
                                           unsigned short* __restrict__ hi,
                                           unsigned short* __restrict__ lo, int idx) {
    float4 v = ((const float4*)src)[idx];
    ushort2 h01, h23, l01, l23;
    unsigned short h;
    h = f2b(v.x); h01.x = h; l01.x = f2b(v.x - b2f(h));
    h = f2b(v.y); h01.y = h; l01.y = f2b(v.y - b2f(h));
    h = f2b(v.z); h23.x = h; l23.x = f2b(v.z - b2f(h));
    h = f2b(v.w); h23.y = h; l23.y = f2b(v.w - b2f(h));
    ((ushort2*)hi)[idx * 2] = h01; ((ushort2*)hi)[idx * 2 + 1] = h23;
    ((ushort2*)lo)[idx * 2] = l01; ((ushort2*)lo)[idx * 2 + 1] = l23;
}
__device__ __forceinline__ void cvt_one4(const float* __restrict__ src,
                                         unsigned short* __restrict__ dst, int idx) {
    float4 v = ((const float4*)src)[idx];
    ushort2 h01, h23;
    h01.x = f2b(v.x); h01.y = f2b(v.y);
    h23.x = f2b(v.z); h23.y = f2b(v.w);
    ((ushort2*)dst)[idx * 2] = h01; ((ushort2*)dst)[idx * 2 + 1] = h23;
}

// ============================================================================
// prep_all: fused prep (one launch, all weight/input conversions + pad-zero)
// ============================================================================
__global__ __launch_bounds__(256) void prep_all(
    const float* __restrict__ x, const float* __restrict__ cw,
    const float* __restrict__ w1, const float* __restrict__ w2,
    const float* __restrict__ w3,
    unsigned short* __restrict__ xhi, unsigned short* __restrict__ xlo,
    unsigned short* __restrict__ chi, unsigned short* __restrict__ clo,
    unsigned short* __restrict__ wchi, unsigned short* __restrict__ wclo,
    unsigned short* __restrict__ w1hi, unsigned short* __restrict__ w1lo,
    unsigned short* __restrict__ w2b, unsigned short* __restrict__ w3b)
{
    int blk = blockIdx.x;
    int t = threadIdx.x;
    if (blk < 2048) {
        int idx = blk * 256 + t;                   // over B*L*D/4 = 524288
        int d4 = idx & 63;
        int l  = (idx >> 6) & 1023;
        int b  = idx >> 16;
        float4 v = ((const float4*)x)[idx];
        size_t o = ((size_t)(b * LPAD + 4 + l) * Dd + d4 * 4) >> 1;
        ushort2 h01, h23, l01, l23;
        unsigned short h;
        h = f2b(v.x); h01.x = h; l01.x = f2b(v.x - b2f(h));
        h = f2b(v.y); h01.y = h; l01.y = f2b(v.y - b2f(h));
        h = f2b(v.z); h23.x = h; l23.x = f2b(v.z - b2f(h));
        h = f2b(v.w); h23.y = h; l23.y = f2b(v.w - b2f(h));
        ((ushort2*)xhi)[o] = h01; ((ushort2*)xhi)[o + 1] = h23;
        ((ushort2*)xlo)[o] = l01; ((ushort2*)xlo)[o + 1] = l23;
    } else if (blk < 4352) {
        int idx = (blk - 2048) * 256 + t;          // 589824 exact
        int i = idx & (Dd - 1);
        int o = (idx >> 8) & (Dd - 1);
        int lk = idx >> 16;
        int layer = lk / 3;
        int k = lk % 3;
        float v = cw[(((size_t)layer * Dd + o) * Dd + i) * 3 + k];
        unsigned short h = f2b(v);
        wchi[idx] = h;
        wclo[idx] = f2b(v - b2f(h));
    } else if (blk < 8448) {
        split_one4(w1, w1hi, w1lo, (blk - 4352) * 256 + t);
    } else if (blk < 16640) {
        cvt_one4(w2, w2b, (blk - 8448) * 256 + t);
    } else if (blk < 24832) {
        cvt_one4(w3, w3b, (blk - 16640) * 256 + t);
    } else {
        // zero pad rows: 4 buffers x (8 batches x 8 rows x 256 elems), 8 elems/thread
        int u = (blk - 24832) * 256 + t;           // [0, 8192)
        int f = u >> 11;
        int rem = u & 2047;
        int b = rem >> 8;
        int r2 = rem & 255;
        int row = r2 >> 5;
        int col = (r2 & 31) * 8;
        int padrow = (row < 4) ? row : (1024 + row);
        unsigned short* buf = (f == 0) ? xhi : (f == 1) ? xlo : (f == 2) ? chi : clo;
        u16x8 z = {0, 0, 0, 0, 0, 0, 0, 0};
        *(u16x8*)(buf + (size_t)(b * LPAD + padrow) * Dd + col) = z;
    }
}

// ============================================================================
// conv_mfma: dilated causal-'same' conv as MFMA NT-GEMM over 3 shifted taps.
// 3-pass split-bf16 (router precision). 64x64 tile, 4 waves (2x2 of 32x32).
// BK=64 (two 32-chunks per barrier pair).  (unchanged from R9/R11)
// ============================================================================
template<int MODE>
__global__ __launch_bounds__(256, 2) void conv_mfma(
    const unsigned short* __restrict__ inhi, const unsigned short* __restrict__ inlo,
    const unsigned short* __restrict__ whiL, const unsigned short* __restrict__ wloL,
    const float* __restrict__ bias,
    unsigned short* __restrict__ outhi, unsigned short* __restrict__ outlo,
    float* __restrict__ outf, int dil)
{
    __shared__ char smem[32768];
    char* sAhi = smem;
    char* sAlo = smem + 8192;
    char* sBhi = smem + 16384;
    char* sBlo = smem + 24576;

    const int t = threadIdx.x;
    const int lane = t & 63, w = t >> 6;
    const int r16 = lane & 15, quad = lane >> 4;
    const int wr = w >> 1, wc = w & 1;
    const int row0 = blockIdx.x * 64;
    const int col0 = blockIdx.y * 64;
    const int b = row0 >> 10, l0 = row0 & 1023;

    int aoff[2], boff[2];
    #pragma unroll
    for (int i = 0; i < 2; ++i) {
        int ra = wr * 32 + i * 16 + r16;
        aoff[i] = ra * 64 + ((quad ^ ((ra >> 1) & 3)) << 4);
        int rb = wc * 32 + i * 16 + r16;
        boff[i] = rb * 64 + ((quad ^ ((rb >> 1) & 3)) << 4);
    }
    const int rs = t >> 2, ce = ((t & 3) ^ ((rs >> 1) & 3)) << 3;
    const unsigned short* gAhi = inhi + (size_t)(b * LPAD + 4 + l0 + rs) * Dd + ce;
    const unsigned short* gAlo = inlo + (size_t)(b * LPAD + 4 + l0 + rs) * Dd + ce;

    f32x4 acc[2][2];
    const f32x4 zero4 = {0.f, 0.f, 0.f, 0.f};
    #pragma unroll
    for (int i = 0; i < 2; ++i)
        #pragma unroll
        for (int j = 0; j < 2; ++j) acc[i][j] = zero4;

    for (int tap = 0; tap < 3; ++tap) {
        const int sh = (tap - 1) * dil;
        const unsigned short* pAhi = gAhi + sh * Dd;
        const unsigned short* pAlo = gAlo + sh * Dd;
        const unsigned short* gBhi = whiL + ((size_t)tap * Dd + col0 + rs) * Dd + ce;
        const unsigned short* gBlo = wloL + ((size_t)tap * Dd + col0 + rs) * Dd + ce;
        for (int kb = 0; kb < Dd; kb += 64) {
            gl_lds16(pAhi + kb,      sAhi + (w << 10));
            gl_lds16(pAhi + kb + 32, sAhi + 4096 + (w << 10));
            gl_lds16(pAlo + kb,      sAlo + (w << 10));
            gl_lds16(pAlo + kb + 32, sAlo + 4096 + (w << 10));
            gl_lds16(gBhi + kb,      sBhi + (w << 10));
            gl_lds16(gBhi + kb + 32, sBhi + 4096 + (w << 10));
            gl_lds16(gBlo + kb,      sBlo + (w << 10));
            gl_lds16(gBlo + kb + 32, sBlo + 4096 + (w << 10));
            __syncthreads();
            #pragma unroll
            for (int h = 0; h < 2; ++h) {
                const int ho = h * 4096;
                bf16x8 ah[2], al[2], bh[2], bl[2];
                #pragma unroll
                for (int i = 0; i < 2; ++i) {
                    ah[i] = *(const bf16x8*)(sAhi + ho + aoff[i]);
                    al[i] = *(const bf16x8*)(sAlo + ho + aoff[i]);
                    bh[i] = *(const bf16x8*)(sBhi + ho + boff[i]);
                    bl[i] = *(const bf16x8*)(sBlo + ho + boff[i]);
                }
                #pragma unroll
                for (int mi = 0; mi < 2; ++mi)
                    #pragma unroll
                    for (int ni = 0; ni < 2; ++ni) {
                        acc[mi][ni] = __builtin_amdgcn_mfma_f32_16x16x32_bf16(ah[mi], bh[ni], acc[mi][ni], 0, 0, 0);
                        acc[mi][ni] = __builtin_amdgcn_mfma_f32_16x16x32_bf16(ah[mi], bl[ni], acc[mi][ni], 0, 0, 0);
                        acc[mi][ni] = __builtin_amdgcn_mfma_f32_16x16x32_bf16(al[mi], bh[ni], acc[mi][ni], 0, 0, 0);
                    }
            }
            __syncthreads();
        }
    }

    int cc[2]; float bv[2];
    #pragma unroll
    for (int ni = 0; ni < 2; ++ni) {
        cc[ni] = col0 + wc * 32 + ni * 16 + r16;
        bv[ni] = bias[cc[ni]];
    }
    #pragma unroll
    for (int mi = 0; mi < 2; ++mi) {
        int lb = l0 + wr * 32 + mi * 16 + quad * 4;
        #pragma unroll
        for (int reg = 0; reg < 4; ++reg) {
            int l = lb + reg;
            #pragma unroll
            for (int ni = 0; ni < 2; ++ni) {
                float v = gelu_f(acc[mi][ni][reg] + bv[ni]);
                if (MODE == 0) {
                    size_t o = (size_t)(b * LPAD + 4 + l) * Dd + cc[ni];
                    unsigned short h = f2b(v);
                    outhi[o] = h;
                    outlo[o] = f2b(v - b2f(h));
                } else {
                    outf[(size_t)(b * Ll + l) * Dd + cc[ni]] = v;
                }
            }
        }
    }
}

// ============================================================================
// Sparse expert GEMM v7: N-strip 8->16 (N=64 tiles) to DOUBLE blocks in
// flight (~1088 blocks = 4.2/CU) — barrier drains of one block hidden by
// another block's compute. XCD = strip%8 (2 strips/XCD in L2, 2 MB) — B
// still fetched ~once; A re-reads absorbed by L3 (A is only ~9 MB).
// Tile M=64 x N=64, 4 waves (2x2, wave-tile 32x32), BK=64.
// TWOPASS=1: B = hi+lo split planes (w1). TWOPASS=0: B plain bf16.
// ============================================================================
template<int MODE, int GATHER, int TWOPASS>
__global__ __launch_bounds__(256, 4) void gemm_sp(
    const unsigned short* __restrict__ AG,
    const unsigned short* __restrict__ BhiG, const unsigned short* __restrict__ BloG,
    const float* __restrict__ biasG, const float* __restrict__ gates,
    const int* __restrict__ cntG, const int* __restrict__ listG,
    const int* __restrict__ tileTab, const int* __restrict__ ntiles,
    unsigned short* __restrict__ Cout, float* __restrict__ outf,
    int M, int N, int K)
{
    if (blockIdx.y >= ntiles[0]) return;          // uniform early-exit
    const int desc = tileTab[blockIdx.y];
    const int e = desc >> 16;
    const int row0 = (desc & 0xffff) * 64;
    const int cn = cntG[e];

    __shared__ char smem[TWOPASS ? 24576 : 16384]; // A 8K | Bhi 8K [| Blo 8K]
    char* sA   = smem;
    char* sBhi = smem + 8192;
    char* sBlo = smem + 16384;                    // used only when TWOPASS

    const unsigned short* Bhi = BhiG + (size_t)e * N * K;
    const unsigned short* Blo = TWOPASS ? (BloG + (size_t)e * N * K) : nullptr;
    const float* bias = biasG + (size_t)e * N;

    const int t = threadIdx.x;
    const int lane = t & 63, w = t >> 6;
    const int r16 = lane & 15, quad = lane >> 4;
    const int wr = w >> 1, wc = w & 1;
    const int col0 = blockIdx.x * 64;

    int aoff[2], boff[2];
    #pragma unroll
    for (int i = 0; i < 2; ++i) {
        int ra = wr * 32 + i * 16 + r16;
        aoff[i] = ra * 64 + ((quad ^ ((ra >> 1) & 3)) << 4);
        int rb = wc * 32 + i * 16 + r16;
        boff[i] = rb * 64 + ((quad ^ ((rb >> 1) & 3)) << 4);
    }
    // staging: 256 slots x 16B per 32-chunk; thread t -> slot t
    const int r0s = t >> 2, c0s = ((t & 3) ^ ((r0s >> 1) & 3)) << 3;
    int ri = row0 + r0s; if (ri > cn - 1) ri = cn - 1;
    const int ar = GATHER ? listG[e * NTOK + ri] : ri;
    const unsigned short* gA  = AG + ((size_t)e * M + ar) * K + c0s;
    const unsigned short* gB  = Bhi + (size_t)(col0 + r0s) * K + c0s;
    const unsigned short* gBl = TWOPASS ? (Blo + (size_t)(col0 + r0s) * K + c0s) : nullptr;
    const int wofs = w << 10;

    f32x4 acc[2][2];
    const f32x4 zero4 = {0.f, 0.f, 0.f, 0.f};
    #pragma unroll
    for (int i = 0; i < 2; ++i)
        #pragma unroll
        for (int j = 0; j < 2; ++j) acc[i][j] = zero4;

    for (int k0 = 0; k0 < K; k0 += 64) {
        gl_lds16(gA + k0,        sA + wofs);
        gl_lds16(gA + k0 + 32,   sA + 4096 + wofs);
        gl_lds16(gB + k0,        sBhi + wofs);
        gl_lds16(gB + k0 + 32,   sBhi + 4096 + wofs);
        if (TWOPASS) {
            gl_lds16(gBl + k0,      sBlo + wofs);
            gl_lds16(gBl + k0 + 32, sBlo + 4096 + wofs);
        }
        __syncthreads();
        #pragma unroll
        for (int h = 0; h < 2; ++h) {
            const int ho = h * 4096;
            bf16x8 ah[2], bh[2];
            #pragma unroll
            for (int i = 0; i < 2; ++i) {
                ah[i] = *(const bf16x8*)(sA + ho + aoff[i]);
                bh[i] = *(const bf16x8*)(sBhi + ho + boff[i]);
            }
            #pragma unroll
            for (int mi = 0; mi < 2; ++mi)
                #pragma unroll
                for (int ni = 0; ni < 2; ++ni)
                    acc[mi][ni] = __builtin_amdgcn_mfma_f32_16x16x32_bf16(ah[mi], bh[ni], acc[mi][ni], 0, 0, 0);
            if (TWOPASS) {
                bf16x8 bl[2];
                #pragma unroll
                for (int i = 0; i < 2; ++i) bl[i] = *(const bf16x8*)(sBlo + ho + boff[i]);
                #pragma unroll
                for (int mi = 0; mi < 2; ++mi)
                    #pragma unroll
                    for (int ni = 0; ni < 2; ++ni)
                        acc[mi][ni] = __builtin_amdgcn_mfma_f32_16x16x32_bf16(ah[mi], bl[ni], acc[mi][ni], 0, 0, 0);
            }
        }
        __syncthreads();
    }

    int cc[2]; float bv[2];
    #pragma unroll
    for (int ni = 0; ni < 2; ++ni) {
        cc[ni] = col0 + wc * 32 + ni * 16 + r16;
        bv[ni] = bias[cc[ni]];
    }
    if (MODE == 0) {
        unsigned short* CE = Cout + (size_t)e * M * N;
        #pragma unroll
        for (int mi = 0; mi < 2; ++mi) {
            int rb = row0 + wr * 32 + mi * 16 + quad * 4;
            #pragma unroll
            for (int reg = 0; reg < 4; ++reg) {
                size_t roff = (size_t)(rb + reg) * N;
                #pragma unroll
                for (int ni = 0; ni < 2; ++ni)
                    CE[roff + cc[ni]] = f2b(gelu_f(acc[mi][ni][reg] + bv[ni]));
            }
        }
    } else {
        #pragma unroll
        for (int mi = 0; mi < 2; ++mi) {
            int rb = row0 + wr * 32 + mi * 16 + quad * 4;
            #pragma unroll
            for (int reg = 0; reg < 4; ++reg) {
                int i = rb + reg;
                if (i < cn) {
                    int tok = listG[e * NTOK + i];
                    float g = gates[(size_t)tok * Ee + e];
                    size_t roff = (size_t)tok * N;
                    #pragma unroll
                    for (int ni = 0; ni < 2; ++ni)
                        atomicAdd(&outf[roff + cc[ni]], g * (acc[mi][ni][reg] + bv[ni]));
                }
            }
        }
    }
}

// ============================ router tail + downsample ==============================

__global__ __launch_bounds__(256) void logits_accum(const float* __restrict__ h,
                                                    const float* __restrict__ fl_w,
                                                    float* __restrict__ logits) {
    int b = blockIdx.x;
    int chunk = blockIdx.y;
    __shared__ float wsm[Ee][128];
    for (int i = threadIdx.x; i < Ee * 128; i += 256) {
        int e = i >> 7, l = i & 127;
        wsm[e][l] = fl_w[e * Ll + chunk * 128 + l];
    }
    __syncthreads();
    int d = threadIdx.x;
    float acc[Ee] = {};
    for (int l = 0; l < 128; ++l) {
        float v = h[((size_t)b * Ll + chunk * 128 + l) * Dd + d];
        #pragma unroll
        for (int e = 0; e < Ee; ++e) acc[e] += v * wsm[e][l];
    }
    int tok = b * Dd + d;
    #pragma unroll
    for (int e = 0; e < Ee; ++e) atomicAdd(&logits[tok * Ee + e], acc[e]);
}

// sigmoid -> softmax -> top2 -> gates + per-expert lists + balanced tile table.
// v2: wave-aggregated list append (ballot + leader LDS atomic + shfl base) —
// replaces 4096 contended value-returning global atomics (~41 us in R11).
// ONE block of 1024 threads (2 toks each); cnt kept in LDS until final store.
__global__ __launch_bounds__(1024) void gates_final(const float* __restrict__ logits,
                                                    const float* __restrict__ fl_b,
                                                    float* __restrict__ gates,
                                                    int* __restrict__ cnt,
                                                    int* __restrict__ list,
                                                    int* __restrict__ tileTab,
                                                    int* __restrict__ ntiles) {
    __shared__ int scnt[Ee];
    if (threadIdx.x < Ee) scnt[threadIdx.x] = 0;
    __syncthreads();
    const int lane = threadIdx.x & 63;
    const unsigned long long ltmask = (1ull << lane) - 1ull;

    for (int tok = threadIdx.x; tok < NTOK; tok += 1024) {   // uniform trip count
        float s[Ee];
        #pragma unroll
        for (int e = 0; e < Ee; ++e) {
            float z = logits[tok * Ee + e] + fl_b[e];
            s[e] = 1.0f / (1.0f + expf(-z));
        }
        float mx = s[0];
        #pragma unroll
        for (int e = 1; e < Ee; ++e) mx = fmaxf(mx, s[e]);
        float p[Ee];
        #pragma unroll
        for (int e = 0; e < Ee; ++e) p[e] = expf(s[e] - mx);
        int i1 = 0;
        #pragma unroll
        for (int e = 1; e < Ee; ++e) if (p[e] > p[i1]) i1 = e;
        int i2 = (i1 == 0) ? 1 : 0;
        #pragma unroll
        for (int e = 0; e < Ee; ++e) {
            if (e == i1 || e == i2) continue;
            if (p[e] > p[i2]) i2 = e;
        }
        float inv = 1.0f / (p[i1] + p[i2]);
        #pragma unroll
        for (int e = 0; e < Ee; ++e) gates[tok * Ee + e] = 0.0f;
        gates[tok * Ee + i1] = p[i1] * inv;
        gates[tok * Ee + i2] = p[i2] * inv;

        // wave-aggregated append for both chosen experts
        #pragma unroll
        for (int slot = 0; slot < 2; ++slot) {
            int ie = slot ? i2 : i1;
            for (int e = 0; e < Ee; ++e) {
                unsigned long long m = __ballot(ie == e);
                if (m) {
                    int leader = __ffsll((long long)m) - 1;
                    int base = 0;
                    if (lane == leader) base = atomicAdd(&scnt[e], (int)__popcll(m));
                    base = __shfl(base, leader);
                    if (ie == e) {
                        int pos = base + (int)__popcll(m & ltmask);
                        list[e * NTOK + pos] = tok;
                    }
                }
            }
        }
    }
    __syncthreads();
    if (threadIdx.x < Ee) cnt[threadIdx.x] = scnt[threadIdx.x];
    if (threadIdx.x == 0) {
        int nt = 0;
        for (int e = 0; e < Ee; ++e) {
            int c = scnt[e];
            for (int m = 0; m * 64 < c; ++m) tileTab[nt++] = (e << 16) | m;
        }
        ntiles[0] = nt;
    }
}

// downsample v3: single bf16 plane, valid region only (xe pad cols hit zero
// w1 cols). 8 j/thread, r-outer for load ILP; early-exit past Li.
__global__ __launch_bounds__(256) void downsample_v3(const float* __restrict__ x,
                                                     unsigned short* __restrict__ xe) {
    int e = blockIdx.z;
    int f = e + 2;
    int Li = Ll / f;
    int j0 = blockIdx.x * 8;
    if (j0 >= Li) return;
    int b = blockIdx.y;
    int d = threadIdx.x;
    float invf = 1.0f / (float)f;
    int lim = Li - 1;
    float v[8] = {};
    for (int r = 0; r < f; ++r) {
        #pragma unroll
        for (int jj = 0; jj < 8; ++jj) {
            int j = j0 + jj; if (j > lim) j = lim;
            v[jj] += x[((size_t)(b * Ll + j * f + r)) * Dd + d];
        }
    }
    size_t obase = ((size_t)(e * NTOK + b * 256 + d)) * LMAXc + j0;
    if (j0 + 8 <= Li) {
        u16x8 hv;
        #pragma unroll
        for (int q = 0; q < 8; ++q) hv[q] = (short)f2b(v[q] * invf);
        *(u16x8*)(xe + obase) = hv;
    } else {
        for (int jj = 0; jj < Li - j0; ++jj)
            xe[obase + jj] = f2b(v[jj] * invf);
    }
}

__global__ __launch_bounds__(256) void transpose_out(const float* __restrict__ outacc,
                                                     float* __restrict__ out) {
    __shared__ float tile[32][33];
    int b = blockIdx.z;
    int d0 = blockIdx.x * 32;
    int o0 = blockIdx.y * 32;
    int tx = threadIdx.x & 31, ty = threadIdx.x >> 5;
    for (int i = 0; i < 32; i += 8)
        tile[ty + i][tx] = outacc[((size_t)b * Dd + d0 + ty + i) * Hh + o0 + tx];
    __syncthreads();
    for (int i = 0; i < 32; i += 8)
        out[((size_t)b * Hh + o0 + ty + i) * Dd + d0 + tx] = tile[tx][ty + i];
}

extern "C" void kernel_launch(void* const* d_in, const int* in_sizes, int n_in,
                              void* d_out, int out_size, void* d_ws, size_t ws_size,
                              hipStream_t stream) {
    const float* x       = (const float*)d_in[0];
    const float* conv_w  = (const float*)d_in[1];
    const float* conv_b  = (const float*)d_in[2];
    const float* fl_w    = (const float*)d_in[3];
    const float* fl_b    = (const float*)d_in[4];
    const float* w1      = (const float*)d_in[5];
    const float* b1      = (const float*)d_in[6];
    const float* w2      = (const float*)d_in[7];
    const float* b2      = (const float*)d_in[8];
    const float* w3      = (const float*)d_in[9];
    const float* b3      = (const float*)d_in[10];
    float* out = (float*)d_out;

    char* ws = (char*)d_ws;
    // Workspace (peak ~134.4 MB). Layout identical to R11.
    unsigned short* xphi = (unsigned short*)(ws);
    unsigned short* xplo = (unsigned short*)(ws + 4227072);
    unsigned short* cphi = (unsigned short*)(ws + 8454144);
    unsigned short* cplo = (unsigned short*)(ws + 12681216);
    unsigned short* wchi = (unsigned short*)(ws + 16908288);
    unsigned short* wclo = (unsigned short*)(ws + 18087936);
    float* hL            = (float*)(ws + 19267584);
    unsigned short* h1   = (unsigned short*)(ws);
    unsigned short* h2   = (unsigned short*)(ws + 33554432);
    unsigned short* xe   = (unsigned short*)(ws + 67108864);
    unsigned short* w1hi = (unsigned short*)(ws + 83886080);
    unsigned short* w1lo = (unsigned short*)(ws + 92274688);
    unsigned short* w2b  = (unsigned short*)(ws + 100663296);
    unsigned short* w3b  = (unsigned short*)(ws + 117440512);
    float* logits  = (float*)(ws + 134217728);
    int*   cnt     = (int*)(ws + 134283264);
    int*   ntiles  = (int*)(ws + 134283296);
    int*   tileTab = (int*)(ws + 134283328);
    float* gates   = (float*)(ws + 134284288);
    int*   list    = (int*)(ws + 134349824);
    float* outacc  = (float*)(ws);

    // zero logits+cnt+ntiles (pad rows handled inside prep_all)
    hipMemsetAsync(logits, 0, 65536 + 64, stream);

    prep_all<<<24864, 256, 0, stream>>>(x, conv_w, w1, w2, w3,
                                        xphi, xplo, cphi, cplo, wchi, wclo,
                                        w1hi, w1lo, w2b, w3b);

    // Router convs on MFMA (3-pass split — ~1e-7 relative, safe for discrete top-2)
    const int WL = 3 * Dd * Dd;
    conv_mfma<0><<<dim3(Bb * Ll / 64, Dd / 64), 256, 0, stream>>>(
        xphi, xplo, wchi + 0 * WL, wclo + 0 * WL, conv_b + 0 * Dd, cphi, cplo, nullptr, 1);
    conv_mfma<0><<<dim3(Bb * Ll / 64, Dd / 64), 256, 0, stream>>>(
        cphi, cplo, wchi + 1 * WL, wclo + 1 * WL, conv_b + 1 * Dd, xphi, xplo, nullptr, 2);
    conv_mfma<1><<<dim3(Bb * Ll / 64, Dd / 64), 256, 0, stream>>>(
        xphi, xplo, wchi + 2 * WL, wclo + 2 * WL, conv_b + 2 * Dd, nullptr, nullptr, hL, 4);

    logits_accum<<<dim3(Bb, 8), 256, 0, stream>>>(hL, fl_w, logits);
    gates_final<<<1, 1024, 0, stream>>>(logits, fl_b, gates, cnt, list, tileTab, ntiles);

    downsample_v3<<<dim3(64, Bb, Ee), 256, 0, stream>>>(x, xe);

    // GEMM1 sparse (gathered A from xe, K=512, w1 split 2-pass): h1 compact
    gemm_sp<0, 1, 1><<<dim3(16, MAXTILES), 256, 0, stream>>>(
        xe, w1hi, w1lo, b1, nullptr, cnt, list, tileTab, ntiles, h1, nullptr, NTOK, Hh, LMAXc);

    // GEMM2 sparse (compact->compact, K=1024, w2 plain bf16 single-pass)
    gemm_sp<0, 0, 0><<<dim3(16, MAXTILES), 256, 0, stream>>>(
        h1, w2b, nullptr, b2, nullptr, cnt, list, tileTab, ntiles, h2, nullptr, NTOK, Hh, Hh);

    // h1 dead: zero outacc in its slot
    hipMemsetAsync(outacc, 0, (size_t)NTOK * Hh * sizeof(float), stream);

    // GEMM3 sparse (compact A, w3 plain bf16, gated scatter-add combine)
    gemm_sp<1, 0, 0><<<dim3(16, MAXTILES), 256, 0, stream>>>(
        h2, w3b, nullptr, b3, gates, cnt, list, tileTab, ntiles, nullptr, outacc, NTOK, Hh, Hh);

    transpose_out<<<dim3(Dd / 32, Hh / 32, Bb), 256, 0, stream>>>(outacc, out);
}

// Round 13
// 311.354 us; speedup vs baseline: 1.2119x; 1.0285x over previous
//
#include <hip/hip_runtime.h>
#include <math.h>

#define Bb 8
#define Ll 1024
#define Dd 256
#define Ee 8
#define Hh 1024
#define LMAXc 512
#define NTOK (Bb*Dd)   // 2048
#define LPAD 1032      // 4 + 1024 + 4 padded token rows per batch
#define MAXTILES 72    // worst-case sum_e ceil(cnt[e]/64): 4096/64 + 7

typedef short bf16x8 __attribute__((ext_vector_type(8)));
typedef float f32x4 __attribute__((ext_vector_type(4)));
typedef unsigned short u16x8 __attribute__((ext_vector_type(8)));

__device__ __forceinline__ float gelu_f(float x) {
    return 0.5f * x * (1.0f + erff(x * 0.70710678118654752440f));
}
__device__ __forceinline__ unsigned short f2b(float x) {          // RTN fp32->bf16
    unsigned int u = __float_as_uint(x);
    return (unsigned short)((u + 0x7fffu + ((u >> 16) & 1u)) >> 16);
}
__device__ __forceinline__ float b2f(unsigned short h) {
    return __uint_as_float(((unsigned int)h) << 16);
}
__device__ __forceinline__ void gl_lds16(const void* g, void* l) {
    __builtin_amdgcn_global_load_lds((const __attribute__((address_space(1))) unsigned int*)g,
                                     (__attribute__((address_space(3))) unsigned int*)l, 16, 0, 0);
}
__device__ __forceinline__ void split_one4(const float* __restrict__ src,
                                           unsigned short* __restrict__ hi,
                                           unsigned short* __restrict__ lo, int idx) {
    float4 v = ((const float4*)src)[idx];
    ushort2 h01, h23, l01, l23;
    unsigned short h;
    h = f2b(v.x); h01.x = h; l01.x = f2b(v.x - b2f(h));
    h = f2b(v.y); h01.y = h; l01.y = f2b(v.y - b2f(h));
    h = f2b(v.z); h23.x = h; l23.x = f2b(v.z - b2f(h));
    h = f2b(v.w); h23.y = h; l23.y = f2b(v.w - b2f(h));
    ((ushort2*)hi)[idx * 2] = h01; ((ushort2*)hi)[idx * 2 + 1] = h23;
    ((ushort2*)lo)[idx * 2] = l01; ((ushort2*)lo)[idx * 2 + 1] = l23;
}
__device__ __forceinline__ void cvt_one4(const float* __restrict__ src,
                                         unsigned short* __restrict__ dst, int idx) {
    float4 v = ((const float4*)src)[idx];
    ushort2 h01, h23;
    h01.x = f2b(v.x); h01.y = f2b(v.y);
    h23.x = f2b(v.z); h23.y = f2b(v.w);
    ((ushort2*)dst)[idx * 2] = h01; ((ushort2*)dst)[idx * 2 + 1] = h23;
}

// ============================================================================
// prep_all: fused prep — all x/weight conversions + pad-zero + downsample.
//   [0,2048)       : pad+split x -> [B][LPAD][D] bf16 hi/lo planes
//   [2048,4352)    : conv weights [3][D][D][3] -> split planes [layer][k][o][i]
//   [4352,8448)    : split w1 (hi/lo)
//   [8448,16640)   : convert w2 -> plain bf16
//   [16640,24832)  : convert w3 -> plain bf16
//   [24832,24864)  : zero pad rows of xphi/xplo/cphi/cplo
//   [24864,28960)  : downsample x -> xe bf16 (e,b,j-chunk; early-exit past Li)
// ============================================================================
__global__ __launch_bounds__(256) void prep_all(
    const float* __restrict__ x, const float* __restrict__ cw,
    const float* __restrict__ w1, const float* __restrict__ w2,
    const float* __restrict__ w3,
    unsigned short* __restrict__ xhi, unsigned short* __restrict__ xlo,
    unsigned short* __restrict__ chi, unsigned short* __restrict__ clo,
    unsigned short* __restrict__ wchi, unsigned short* __restrict__ wclo,
    unsigned short* __restrict__ w1hi, unsigned short* __restrict__ w1lo,
    unsigned short* __restrict__ w2b, unsigned short* __restrict__ w3b,
    unsigned short* __restrict__ xe)
{
    int blk = blockIdx.x;
    int t = threadIdx.x;
    if (blk < 2048) {
        int idx = blk * 256 + t;                   // over B*L*D/4 = 524288
        int d4 = idx & 63;
        int l  = (idx >> 6) & 1023;
        int b  = idx >> 16;
        float4 v = ((const float4*)x)[idx];
        size_t o = ((size_t)(b * LPAD + 4 + l) * Dd + d4 * 4) >> 1;
        ushort2 h01, h23, l01, l23;
        unsigned short h;
        h = f2b(v.x); h01.x = h; l01.x = f2b(v.x - b2f(h));
        h = f2b(v.y); h01.y = h; l01.y = f2b(v.y - b2f(h));
        h = f2b(v.z); h23.x = h; l23.x = f2b(v.z - b2f(h));
        h = f2b(v.w); h23.y = h; l23.y = f2b(v.w - b2f(h));
        ((ushort2*)xhi)[o] = h01; ((ushort2*)xhi)[o + 1] = h23;
        ((ushort2*)xlo)[o] = l01; ((ushort2*)xlo)[o + 1] = l23;
    } else if (blk < 4352) {
        int idx = (blk - 2048) * 256 + t;          // 589824 exact
        int i = idx & (Dd - 1);
        int o = (idx >> 8) & (Dd - 1);
        int lk = idx >> 16;
        int layer = lk / 3;
        int k = lk % 3;
        float v = cw[(((size_t)layer * Dd + o) * Dd + i) * 3 + k];
        unsigned short h = f2b(v);
        wchi[idx] = h;
        wclo[idx] = f2b(v - b2f(h));
    } else if (blk < 8448) {
        split_one4(w1, w1hi, w1lo, (blk - 4352) * 256 + t);
    } else if (blk < 16640) {
        cvt_one4(w2, w2b, (blk - 8448) * 256 + t);
    } else if (blk < 24832) {
        cvt_one4(w3, w3b, (blk - 16640) * 256 + t);
    } else if (blk < 24864) {
        // zero pad rows: 4 buffers x (8 batches x 8 rows x 256 elems)
        int u = (blk - 24832) * 256 + t;           // [0, 8192)
        int f = u >> 11;
        int rem = u & 2047;
        int b = rem >> 8;
        int r2 = rem & 255;
        int row = r2 >> 5;
        int col = (r2 & 31) * 8;
        int padrow = (row < 4) ? row : (1024 + row);
        unsigned short* buf = (f == 0) ? xhi : (f == 1) ? xlo : (f == 2) ? chi : clo;
        u16x8 z = {0, 0, 0, 0, 0, 0, 0, 0};
        *(u16x8*)(buf + (size_t)(b * LPAD + padrow) * Dd + col) = z;
    } else {
        // downsample: u = (e*8 + b)*64 + c;  j0 = c*8; threads = d
        int u = blk - 24864;                       // [0, 4096)
        int e = u >> 9;
        int b = (u >> 6) & 7;
        int c = u & 63;
        int f = e + 2;
        int Li = Ll / f;
        int j0 = c * 8;
        if (j0 >= Li) return;
        int d = t;
        float invf = 1.0f / (float)f;
        int lim = Li - 1;
        float v[8] = {};
        for (int r = 0; r < f; ++r) {
            #pragma unroll
            for (int jj = 0; jj < 8; ++jj) {
                int j = j0 + jj; if (j > lim) j = lim;
                v[jj] += x[((size_t)(b * Ll + j * f + r)) * Dd + d];
            }
        }
        size_t obase = ((size_t)(e * NTOK + b * 256 + d)) * LMAXc + j0;
        if (j0 + 8 <= Li) {
            u16x8 hv;
            #pragma unroll
            for (int q = 0; q < 8; ++q) hv[q] = (short)f2b(v[q] * invf);
            *(u16x8*)(xe + obase) = hv;
        } else {
            for (int jj = 0; jj < Li - j0; ++jj)
                xe[obase + jj] = f2b(v[jj] * invf);
        }
    }
}

// ============================================================================
// conv_mfma: dilated causal-'same' conv as MFMA NT-GEMM over 3 shifted taps.
// 3-pass split-bf16 (router precision). 64x64 tile, 4 waves (2x2 of 32x32).
// BK=64 (two 32-chunks per barrier pair).  (unchanged from R9/R11/R12)
// ============================================================================
template<int MODE>
__global__ __launch_bounds__(256, 2) void conv_mfma(
    const unsigned short* __restrict__ inhi, const unsigned short* __restrict__ inlo,
    const unsigned short* __restrict__ whiL, const unsigned short* __restrict__ wloL,
    const float* __restrict__ bias,
    unsigned short* __restrict__ outhi, unsigned short* __restrict__ outlo,
    float* __restrict__ outf, int dil)
{
    __shared__ char smem[32768];
    char* sAhi = smem;
    char* sAlo = smem + 8192;
    char* sBhi = smem + 16384;
    char* sBlo = smem + 24576;

    const int t = threadIdx.x;
    const int lane = t & 63, w = t >> 6;
    const int r16 = lane & 15, quad = lane >> 4;
    const int wr = w >> 1, wc = w & 1;
    const int row0 = blockIdx.x * 64;
    const int col0 = blockIdx.y * 64;
    const int b = row0 >> 10, l0 = row0 & 1023;

    int aoff[2], boff[2];
    #pragma unroll
    for (int i = 0; i < 2; ++i) {
        int ra = wr * 32 + i * 16 + r16;
        aoff[i] = ra * 64 + ((quad ^ ((ra >> 1) & 3)) << 4);
        int rb = wc * 32 + i * 16 + r16;
        boff[i] = rb * 64 + ((quad ^ ((rb >> 1) & 3)) << 4);
    }
    const int rs = t >> 2, ce = ((t & 3) ^ ((rs >> 1) & 3)) << 3;
    const unsigned short* gAhi = inhi + (size_t)(b * LPAD + 4 + l0 + rs) * Dd + ce;
    const unsigned short* gAlo = inlo + (size_t)(b * LPAD + 4 + l0 + rs) * Dd + ce;

    f32x4 acc[2][2];
    const f32x4 zero4 = {0.f, 0.f, 0.f, 0.f};
    #pragma unroll
    for (int i = 0; i < 2; ++i)
        #pragma unroll
        for (int j = 0; j < 2; ++j) acc[i][j] = zero4;

    for (int tap = 0; tap < 3; ++tap) {
        const int sh = (tap - 1) * dil;
        const unsigned short* pAhi = gAhi + sh * Dd;
        const unsigned short* pAlo = gAlo + sh * Dd;
        const unsigned short* gBhi = whiL + ((size_t)tap * Dd + col0 + rs) * Dd + ce;
        const unsigned short* gBlo = wloL + ((size_t)tap * Dd + col0 + rs) * Dd + ce;
        for (int kb = 0; kb < Dd; kb += 64) {
            gl_lds16(pAhi + kb,      sAhi + (w << 10));
            gl_lds16(pAhi + kb + 32, sAhi + 4096 + (w << 10));
            gl_lds16(pAlo + kb,      sAlo + (w << 10));
            gl_lds16(pAlo + kb + 32, sAlo + 4096 + (w << 10));
            gl_lds16(gBhi + kb,      sBhi + (w << 10));
            gl_lds16(gBhi + kb + 32, sBhi + 4096 + (w << 10));
            gl_lds16(gBlo + kb,      sBlo + (w << 10));
            gl_lds16(gBlo + kb + 32, sBlo + 4096 + (w << 10));
            __syncthreads();
            #pragma unroll
            for (int h = 0; h < 2; ++h) {
                const int ho = h * 4096;
                bf16x8 ah[2], al[2], bh[2], bl[2];
                #pragma unroll
                for (int i = 0; i < 2; ++i) {
                    ah[i] = *(const bf16x8*)(sAhi + ho + aoff[i]);
                    al[i] = *(const bf16x8*)(sAlo + ho + aoff[i]);
                    bh[i] = *(const bf16x8*)(sBhi + ho + boff[i]);
                    bl[i] = *(const bf16x8*)(sBlo + ho + boff[i]);
                }
                #pragma unroll
                for (int mi = 0; mi < 2; ++mi)
                    #pragma unroll
                    for (int ni = 0; ni < 2; ++ni) {
                        acc[mi][ni] = __builtin_amdgcn_mfma_f32_16x16x32_bf16(ah[mi], bh[ni], acc[mi][ni], 0, 0, 0);
                        acc[mi][ni] = __builtin_amdgcn_mfma_f32_16x16x32_bf16(ah[mi], bl[ni], acc[mi][ni], 0, 0, 0);
                        acc[mi][ni] = __builtin_amdgcn_mfma_f32_16x16x32_bf16(al[mi], bh[ni], acc[mi][ni], 0, 0, 0);
                    }
            }
            __syncthreads();
        }
    }

    int cc[2]; float bv[2];
    #pragma unroll
    for (int ni = 0; ni < 2; ++ni) {
        cc[ni] = col0 + wc * 32 + ni * 16 + r16;
        bv[ni] = bias[cc[ni]];
    }
    #pragma unroll
    for (int mi = 0; mi < 2; ++mi) {
        int lb = l0 + wr * 32 + mi * 16 + quad * 4;
        #pragma unroll
        for (int reg = 0; reg < 4; ++reg) {
            int l = lb + reg;
            #pragma unroll
            for (int ni = 0; ni < 2; ++ni) {
                float v = gelu_f(acc[mi][ni][reg] + bv[ni]);
                if (MODE == 0) {
                    size_t o = (size_t)(b * LPAD + 4 + l) * Dd + cc[ni];
                    unsigned short h = f2b(v);
                    outhi[o] = h;
                    outlo[o] = f2b(v - b2f(h));
                } else {
                    outf[(size_t)(b * Ll + l) * Dd + cc[ni]] = v;
                }
            }
        }
    }
}

// ============================================================================
// Sparse expert GEMM v8: balanced flat tile dispatch, XCD strips.
// TWOPASS=1 (gemm1/w1 split): BK=64, LDS 24KB, per-expert K-cap (w1 cols
//   beyond Li=1024/(e+2) are exactly zero -> skip them).
// TWOPASS=0 (gemm2/3, plain-bf16 B): BK=128, LDS 32KB — 4 blocks/CU x 32KB
//   = 128KB <= 160KB: HALF the barrier-drain events at unchanged occupancy.
// Tile M=64 x N=64, 4 waves (2x2, wave-tile 32x32). Grid (16, MAXTILES).
// ============================================================================
template<int MODE, int GATHER, int TWOPASS>
__global__ __launch_bounds__(256, 4) void gemm_sp(
    const unsigned short* __restrict__ AG,
    const unsigned short* __restrict__ BhiG, const unsigned short* __restrict__ BloG,
    const float* __restrict__ biasG, const float* __restrict__ gates,
    const int* __restrict__ cntG, const int* __restrict__ listG,
    const int* __restrict__ tileTab, const int* __restrict__ ntiles,
    unsigned short* __restrict__ Cout, float* __restrict__ outf,
    int M, int N, int K)
{
    if (blockIdx.y >= ntiles[0]) return;          // uniform early-exit
    const int desc = tileTab[blockIdx.y];
    const int e = desc >> 16;
    const int row0 = (desc & 0xffff) * 64;
    const int cn = cntG[e];

    constexpr int NCH = TWOPASS ? 2 : 4;          // 32-col chunks per K-iter
    __shared__ char smem[TWOPASS ? 24576 : 32768]; // A NCH*4K | Bhi NCH*4K [| Blo 8K]
    char* sA   = smem;
    char* sBhi = smem + NCH * 4096;
    char* sBlo = smem + 2 * NCH * 4096;           // TWOPASS only

    const unsigned short* Bhi = BhiG + (size_t)e * N * K;
    const unsigned short* Blo = TWOPASS ? (BloG + (size_t)e * N * K) : nullptr;
    const float* bias = biasG + (size_t)e * N;

    // per-expert K-cap for gemm1: w1 cols >= Li are exactly zero
    int Keff = K;
    if (GATHER) {
        int Li = Ll / (e + 2);
        Keff = ((Li + 63) >> 6) << 6;
    }

    const int t = threadIdx.x;
    const int lane = t & 63, w = t >> 6;
    const int r16 = lane & 15, quad = lane >> 4;
    const int wr = w >> 1, wc = w & 1;
    const int col0 = blockIdx.x * 64;

    int aoff[2], boff[2];
    #pragma unroll
    for (int i = 0; i < 2; ++i) {
        int ra = wr * 32 + i * 16 + r16;
        aoff[i] = ra * 64 + ((quad ^ ((ra >> 1) & 3)) << 4);
        int rb = wc * 32 + i * 16 + r16;
        boff[i] = rb * 64 + ((quad ^ ((rb >> 1) & 3)) << 4);
    }
    const int r0s = t >> 2, c0s = ((t & 3) ^ ((r0s >> 1) & 3)) << 3;
    int ri = row0 + r0s; if (ri > cn - 1) ri = cn - 1;
    const int ar = GATHER ? listG[e * NTOK + ri] : ri;
    const unsigned short* gA  = AG + ((size_t)e * M + ar) * K + c0s;
    const unsigned short* gB  = Bhi + (size_t)(col0 + r0s) * K + c0s;
    const unsigned short* gBl = TWOPASS ? (Blo + (size_t)(col0 + r0s) * K + c0s) : nullptr;
    const int wofs = w << 10;

    f32x4 acc[2][2];
    const f32x4 zero4 = {0.f, 0.f, 0.f, 0.f};
    #pragma unroll
    for (int i = 0; i < 2; ++i)
        #pragma unroll
        for (int j = 0; j < 2; ++j) acc[i][j] = zero4;

    for (int k0 = 0; k0 < Keff; k0 += NCH * 32) {
        #pragma unroll
        for (int c = 0; c < NCH; ++c) {
            gl_lds16(gA + k0 + c * 32, sA + c * 4096 + wofs);
            gl_lds16(gB + k0 + c * 32, sBhi + c * 4096 + wofs);
        }
        if (TWOPASS) {
            #pragma unroll
            for (int c = 0; c < NCH; ++c)
                gl_lds16(gBl + k0 + c * 32, sBlo + c * 4096 + wofs);
        }
        __syncthreads();
        #pragma unroll
        for (int h = 0; h < NCH; ++h) {
            const int ho = h * 4096;
            bf16x8 ah[2], bh[2];
            #pragma unroll
            for (int i = 0; i < 2; ++i) {
                ah[i] = *(const bf16x8*)(sA + ho + aoff[i]);
                bh[i] = *(const bf16x8*)(sBhi + ho + boff[i]);
            }
            #pragma unroll
            for (int mi = 0; mi < 2; ++mi)
                #pragma unroll
                for (int ni = 0; ni < 2; ++ni)
                    acc[mi][ni] = __builtin_amdgcn_mfma_f32_16x16x32_bf16(ah[mi], bh[ni], acc[mi][ni], 0, 0, 0);
            if (TWOPASS) {
                bf16x8 bl[2];
                #pragma unroll
                for (int i = 0; i < 2; ++i) bl[i] = *(const bf16x8*)(sBlo + ho + boff[i]);
                #pragma unroll
                for (int mi = 0; mi < 2; ++mi)
                    #pragma unroll
                    for (int ni = 0; ni < 2; ++ni)
                        acc[mi][ni] = __builtin_amdgcn_mfma_f32_16x16x32_bf16(ah[mi], bl[ni], acc[mi][ni], 0, 0, 0);
            }
        }
        __syncthreads();
    }

    int cc[2]; float bv[2];
    #pragma unroll
    for (int ni = 0; ni < 2; ++ni) {
        cc[ni] = col0 + wc * 32 + ni * 16 + r16;
        bv[ni] = bias[cc[ni]];
    }
    if (MODE == 0) {
        unsigned short* CE = Cout + (size_t)e * M * N;
        #pragma unroll
        for (int mi = 0; mi < 2; ++mi) {
            int rb = row0 + wr * 32 + mi * 16 + quad * 4;
            #pragma unroll
            for (int reg = 0; reg < 4; ++reg) {
                size_t roff = (size_t)(rb + reg) * N;
                #pragma unroll
                for (int ni = 0; ni < 2; ++ni)
                    CE[roff + cc[ni]] = f2b(gelu_f(acc[mi][ni][reg] + bv[ni]));
            }
        }
    } else {
        #pragma unroll
        for (int mi = 0; mi < 2; ++mi) {
            int rb = row0 + wr * 32 + mi * 16 + quad * 4;
            #pragma unroll
            for (int reg = 0; reg < 4; ++reg) {
                int i = rb + reg;
                if (i < cn) {
                    int tok = listG[e * NTOK + i];
                    float g = gates[(size_t)tok * Ee + e];
                    size_t roff = (size_t)tok * N;
                    #pragma unroll
                    for (int ni = 0; ni < 2; ++ni)
                        atomicAdd(&outf[roff + cc[ni]], g * (acc[mi][ni][reg] + bv[ni]));
                }
            }
        }
    }
}

// ============================ router tail ==============================

__global__ __launch_bounds__(256) void logits_accum(const float* __restrict__ h,
                                                    const float* __restrict__ fl_w,
                                                    float* __restrict__ logits) {
    int b = blockIdx.x;
    int chunk = blockIdx.y;
    __shared__ float wsm[Ee][128];
    for (int i = threadIdx.x; i < Ee * 128; i += 256) {
        int e = i >> 7, l = i & 127;
        wsm[e][l] = fl_w[e * Ll + chunk * 128 + l];
    }
    __syncthreads();
    int d = threadIdx.x;
    float acc[Ee] = {};
    for (int l = 0; l < 128; ++l) {
        float v = h[((size_t)b * Ll + chunk * 128 + l) * Dd + d];
        #pragma unroll
        for (int e = 0; e < Ee; ++e) acc[e] += v * wsm[e][l];
    }
    int tok = b * Dd + d;
    #pragma unroll
    for (int e = 0; e < Ee; ++e) atomicAdd(&logits[tok * Ee + e], acc[e]);
}

// sigmoid -> softmax -> top2 -> gates + per-expert lists + balanced tile table.
// Wave-aggregated list append (ballot + leader LDS atomic + shfl base).
__global__ __launch_bounds__(1024) void gates_final(const float* __restrict__ logits,
                                                    const float* __restrict__ fl_b,
                                                    float* __restrict__ gates,
                                                    int* __restrict__ cnt,
                                                    int* __restrict__ list,
                                                    int* __restrict__ tileTab,
                                                    int* __restrict__ ntiles) {
    __shared__ int scnt[Ee];
    if (threadIdx.x < Ee) scnt[threadIdx.x] = 0;
    __syncthreads();
    const int lane = threadIdx.x & 63;
    const unsigned long long ltmask = (1ull << lane) - 1ull;

    for (int tok = threadIdx.x; tok < NTOK; tok += 1024) {
        float s[Ee];
        #pragma unroll
        for (int e = 0; e < Ee; ++e) {
            float z = logits[tok * Ee + e] + fl_b[e];
            s[e] = 1.0f / (1.0f + expf(-z));
        }
        float mx = s[0];
        #pragma unroll
        for (int e = 1; e < Ee; ++e) mx = fmaxf(mx, s[e]);
        float p[Ee];
        #pragma unroll
        for (int e = 0; e < Ee; ++e) p[e] = expf(s[e] - mx);
        int i1 = 0;
        #pragma unroll
        for (int e = 1; e < Ee; ++e) if (p[e] > p[i1]) i1 = e;
        int i2 = (i1 == 0) ? 1 : 0;
        #pragma unroll
        for (int e = 0; e < Ee; ++e) {
            if (e == i1 || e == i2) continue;
            if (p[e] > p[i2]) i2 = e;
        }
        float inv = 1.0f / (p[i1] + p[i2]);
        #pragma unroll
        for (int e = 0; e < Ee; ++e) gates[tok * Ee + e] = 0.0f;
        gates[tok * Ee + i1] = p[i1] * inv;
        gates[tok * Ee + i2] = p[i2] * inv;

        #pragma unroll
        for (int slot = 0; slot < 2; ++slot) {
            int ie = slot ? i2 : i1;
            for (int e = 0; e < Ee; ++e) {
                unsigned long long m = __ballot(ie == e);
                if (m) {
                    int leader = __ffsll((long long)m) - 1;
                    int base = 0;
                    if (lane == leader) base = atomicAdd(&scnt[e], (int)__popcll(m));
                    base = __shfl(base, leader);
                    if (ie == e) {
                        int pos = base + (int)__popcll(m & ltmask);
                        list[e * NTOK + pos] = tok;
                    }
                }
            }
        }
    }
    __syncthreads();
    if (threadIdx.x < Ee) cnt[threadIdx.x] = scnt[threadIdx.x];
    if (threadIdx.x == 0) {
        int nt = 0;
        for (int e = 0; e < Ee; ++e) {
            int c = scnt[e];
            for (int m = 0; m * 64 < c; ++m) tileTab[nt++] = (e << 16) | m;
        }
        ntiles[0] = nt;
    }
}

__global__ __launch_bounds__(256) void transpose_out(const float* __restrict__ outacc,
                                                     float* __restrict__ out) {
    __shared__ float tile[32][33];
    int b = blockIdx.z;
    int d0 = blockIdx.x * 32;
    int o0 = blockIdx.y * 32;
    int tx = threadIdx.x & 31, ty = threadIdx.x >> 5;
    for (int i = 0; i < 32; i += 8)
        tile[ty + i][tx] = outacc[((size_t)b * Dd + d0 + ty + i) * Hh + o0 + tx];
    __syncthreads();
    for (int i = 0; i < 32; i += 8)
        out[((size_t)b * Hh + o0 + ty + i) * Dd + d0 + tx] = tile[tx][ty + i];
}

extern "C" void kernel_launch(void* const* d_in, const int* in_sizes, int n_in,
                              void* d_out, int out_size, void* d_ws, size_t ws_size,
                              hipStream_t stream) {
    const float* x       = (const float*)d_in[0];
    const float* conv_w  = (const float*)d_in[1];
    const float* conv_b  = (const float*)d_in[2];
    const float* fl_w    = (const float*)d_in[3];
    const float* fl_b    = (const float*)d_in[4];
    const float* w1      = (const float*)d_in[5];
    const float* b1      = (const float*)d_in[6];
    const float* w2      = (const float*)d_in[7];
    const float* b2      = (const float*)d_in[8];
    const float* w3      = (const float*)d_in[9];
    const float* b3      = (const float*)d_in[10];
    float* out = (float*)d_out;

    char* ws = (char*)d_ws;
    // Workspace (peak ~134.4 MB). Layout identical to R11/R12.
    unsigned short* xphi = (unsigned short*)(ws);
    unsigned short* xplo = (unsigned short*)(ws + 4227072);
    unsigned short* cphi = (unsigned short*)(ws + 8454144);
    unsigned short* cplo = (unsigned short*)(ws + 12681216);
    unsigned short* wchi = (unsigned short*)(ws + 16908288);
    unsigned short* wclo = (unsigned short*)(ws + 18087936);
    float* hL            = (float*)(ws + 19267584);
    unsigned short* h1   = (unsigned short*)(ws);
    unsigned short* h2   = (unsigned short*)(ws + 33554432);
    unsigned short* xe   = (unsigned short*)(ws + 67108864);
    unsigned short* w1hi = (unsigned short*)(ws + 83886080);
    unsigned short* w1lo = (unsigned short*)(ws + 92274688);
    unsigned short* w2b  = (unsigned short*)(ws + 100663296);
    unsigned short* w3b  = (unsigned short*)(ws + 117440512);
    float* logits  = (float*)(ws + 134217728);
    int*   cnt     = (int*)(ws + 134283264);
    int*   ntiles  = (int*)(ws + 134283296);
    int*   tileTab = (int*)(ws + 134283328);
    float* gates   = (float*)(ws + 134284288);
    int*   list    = (int*)(ws + 134349824);
    float* outacc  = (float*)(ws);

    // zero logits+cnt+ntiles (pad rows handled inside prep_all)
    hipMemsetAsync(logits, 0, 65536 + 64, stream);

    prep_all<<<28960, 256, 0, stream>>>(x, conv_w, w1, w2, w3,
                                        xphi, xplo, cphi, cplo, wchi, wclo,
                                        w1hi, w1lo, w2b, w3b, xe);

    // Router convs on MFMA (3-pass split — ~1e-7 relative, safe for discrete top-2)
    const int WL = 3 * Dd * Dd;
    conv_mfma<0><<<dim3(Bb * Ll / 64, Dd / 64), 256, 0, stream>>>(
        xphi, xplo, wchi + 0 * WL, wclo + 0 * WL, conv_b + 0 * Dd, cphi, cplo, nullptr, 1);
    conv_mfma<0><<<dim3(Bb * Ll / 64, Dd / 64), 256, 0, stream>>>(
        cphi, cplo, wchi + 1 * WL, wclo + 1 * WL, conv_b + 1 * Dd, xphi, xplo, nullptr, 2);
    conv_mfma<1><<<dim3(Bb * Ll / 64, Dd / 64), 256, 0, stream>>>(
        xphi, xplo, wchi + 2 * WL, wclo + 2 * WL, conv_b + 2 * Dd, nullptr, nullptr, hL, 4);

    logits_accum<<<dim3(Bb, 8), 256, 0, stream>>>(hL, fl_w, logits);
    gates_final<<<1, 1024, 0, stream>>>(logits, fl_b, gates, cnt, list, tileTab, ntiles);

    // GEMM1 sparse (gathered A from xe, per-expert K-cap, w1 split 2-pass)
    gemm_sp<0, 1, 1><<<dim3(16, MAXTILES), 256, 0, stream>>>(
        xe, w1hi, w1lo, b1, nullptr, cnt, list, tileTab, ntiles, h1, nullptr, NTOK, Hh, LMAXc);

    // GEMM2 sparse (compact->compact, K=1024, plain bf16 B, BK=128)
    gemm_sp<0, 0, 0><<<dim3(16, MAXTILES), 256, 0, stream>>>(
        h1, w2b, nullptr, b2, nullptr, cnt, list, tileTab, ntiles, h2, nullptr, NTOK, Hh, Hh);

    // h1 dead: zero outacc in its slot
    hipMemsetAsync(outacc, 0, (size_t)NTOK * Hh * sizeof(float), stream);

    // GEMM3 sparse (compact A, plain bf16 B, BK=128, gated scatter-add)
    gemm_sp<1, 0, 0><<<dim3(16, MAXTILES), 256, 0, stream>>>(
        h2, w3b, nullptr, b3, gates, cnt, list, tileTab, ntiles, nullptr, outacc, NTOK, Hh, Hh);

    transpose_out<<<dim3(Dd / 32, Hh / 32, Bb), 256, 0, stream>>>(outacc, out);
}